// Round 3
// baseline (2061.192 us; speedup 1.0000x reference)
//
#include <hip/hip_runtime.h>
#include <hip/hip_bf16.h>

// Problem constants (fixed by the reference)
#define B_  64
#define T_  128
#define E_  300
#define EP  320     // E padded to multiple of 32 for MFMA K-loop
#define H_  512
#define G4  2048    // 4*H
#define R_  128     // 2*B (s1+s2 batched; shared LSTM weights)
#define C_  256
#define M_  512
#define TS  (T_ + 1)  // h time slots: slot 0 = h0, slot t+1 = h(t)
#define NB  128     // persistent-kernel grid: 2 streams x 4 rowblocks x 16 jblocks

typedef short bf16x8 __attribute__((ext_vector_type(8)));
typedef float f32x4  __attribute__((ext_vector_type(4)));
#define MFMA(a, b, c) __builtin_amdgcn_mfma_f32_16x16x32_bf16((a), (b), (c), 0, 0, 0)

__device__ __forceinline__ float fsig(float x) { return 1.0f / (1.0f + __expf(-x)); }
__device__ __forceinline__ float ftanh(float x) {
    float a = fminf(fabsf(x), 15.0f);
    float e = __expf(2.0f * a);
    return copysignf((e - 1.0f) / (e + 1.0f), x);
}
__device__ __forceinline__ ushort f2bf(float f) {
    __hip_bfloat16 h = __float2bfloat16(f);
    return *reinterpret_cast<ushort*>(&h);
}
__device__ __forceinline__ float bf2f(ushort u) {
    __hip_bfloat16 h = *reinterpret_cast<__hip_bfloat16*>(&u);
    return __bfloat162float(h);
}

// ---------------------------------------------------------------------------
// P0: fused f32 -> bf16 conversion for ALL weight tensors + h0 init.
// Blocks [0,40448): weight regions (K-padding zeros in [sk,dk)).
// Blocks [40448, 40576): h slot-0 init from h0 inputs.
// (round-0 measured-best version)
// ---------------------------------------------------------------------------
__global__ __launch_bounds__(256) void k_cvt_all(
    const float* __restrict__ emb,
    const float* __restrict__ Wih_f, const float* __restrict__ Wih_b,
    const float* __restrict__ Whh_f, const float* __restrict__ Whh_b,
    const float* __restrict__ S1W,
    const float* __restrict__ s1_h0, const float* __restrict__ s2_h0,
    ushort* __restrict__ embB,
    ushort* __restrict__ WihBf, ushort* __restrict__ WihBb,
    ushort* __restrict__ WhhBf, ushort* __restrict__ WhhBb,
    ushort* __restrict__ S1WB,
    ushort* __restrict__ hfB, ushort* __restrict__ hbB)
{
    int b = blockIdx.x;
    if (b >= 40448) {   // h0 init role
        const int r = b - 40448;                     // 0..127
        const int rl = (r < B_) ? r : r - B_;
        const float* h0 = (r < B_) ? s1_h0 : s2_h0;  // [2][B][H]
        for (int j = threadIdx.x; j < H_; j += 256) {
            hfB[(long)r * TS * H_ + j] = f2bf(h0[(long)0 * B_ * H_ + (long)rl * H_ + j]);
            hbB[(long)r * TS * H_ + j] = f2bf(h0[(long)1 * B_ * H_ + (long)rl * H_ + j]);
        }
        return;
    }
    const float* src; ushort* dst; int r, sk, dk;
    if (b < 32000)      { src = emb;   dst = embB;  r = b;          sk = E_;    dk = EP; }
    else if (b < 34048) { src = Wih_f; dst = WihBf; r = b - 32000;  sk = E_;    dk = EP; }
    else if (b < 36096) { src = Wih_b; dst = WihBb; r = b - 34048;  sk = E_;    dk = EP; }
    else if (b < 38144) { src = Whh_f; dst = WhhBf; r = b - 36096;  sk = H_;    dk = H_; }
    else if (b < 40192) { src = Whh_b; dst = WhhBb; r = b - 38144;  sk = H_;    dk = H_; }
    else                { src = S1W;   dst = S1WB;  r = b - 40192;  sk = 2*H_;  dk = 2*H_; }
    for (int c = threadIdx.x; c < dk; c += 256)
        dst[(long)r * dk + c] = (c < sk) ? f2bf(src[(long)r * sk + c]) : (ushort)0;
}

// ---------------------------------------------------------------------------
// K1: embedding gather + input GEMM via bf16 MFMA (round-0 verbatim).
// ---------------------------------------------------------------------------
__global__ __launch_bounds__(256) void k_embed_mfma(
    const int* __restrict__ s1, const int* __restrict__ s2,
    const int* __restrict__ l1, const int* __restrict__ l2,
    const ushort* __restrict__ embB,
    const ushort* __restrict__ WihBf, const ushort* __restrict__ WihBb,
    const float* __restrict__ b_f, const float* __restrict__ b_b,
    ushort* __restrict__ xf, ushort* __restrict__ xb)
{
    const int dir = blockIdx.z;
    const int r   = blockIdx.y >> 1;
    const int t0  = (blockIdx.y & 1) * 64;
    const int N0  = blockIdx.x * 128;
    const int L   = (r < B_) ? l1[r] : l2[r - B_];
    if (L <= t0) return;

    const int tid = threadIdx.x;
    const int lane = tid & 63, w = tid >> 6;
    const int wm = w & 1, wn = w >> 1;
    const int l15 = lane & 15, q8 = (lane >> 4) * 8;

    __shared__ int toks[64];
    __shared__ __align__(16) ushort As[64][40];
    __shared__ __align__(16) ushort Bs[128][40];

    if (tid < 64) {
        int t  = t0 + tid;
        int tt = dir ? ((t < L) ? (L - 1 - t) : t) : t;
        toks[tid] = (r < B_) ? s1[r * T_ + tt] : s2[(r - B_) * T_ + tt];
    }
    __syncthreads();

    const ushort* Wih  = dir ? WihBb : WihBf;
    const float*  bias = dir ? b_b : b_f;

    f32x4 acc[2][4] = {};

    for (int k0 = 0; k0 < EP; k0 += 32) {
        {   // A: 64 rows x 32 k
            int row = tid >> 2, seg = tid & 3;
            *(uint4*)&As[row][seg * 8] =
                *(const uint4*)&embB[(long)toks[row] * EP + k0 + seg * 8];
        }
#pragma unroll
        for (int p = 0; p < 2; ++p) {   // B: 128 cols x 32 k
            int u = tid + p * 256;
            int row = u >> 2, seg = u & 3;
            *(uint4*)&Bs[row][seg * 8] =
                *(const uint4*)&Wih[(long)(N0 + row) * EP + k0 + seg * 8];
        }
        __syncthreads();
        bf16x8 af[2], bfr[4];
#pragma unroll
        for (int mt = 0; mt < 2; ++mt)
            af[mt] = *(const bf16x8*)&As[wm * 32 + mt * 16 + l15][q8];
#pragma unroll
        for (int nt = 0; nt < 4; ++nt)
            bfr[nt] = *(const bf16x8*)&Bs[wn * 64 + nt * 16 + l15][q8];
#pragma unroll
        for (int mt = 0; mt < 2; ++mt)
#pragma unroll
            for (int nt = 0; nt < 4; ++nt)
                acc[mt][nt] = MFMA(af[mt], bfr[nt], acc[mt][nt]);
        __syncthreads();
    }

    ushort* xout = dir ? xb : xf;
#pragma unroll
    for (int mt = 0; mt < 2; ++mt) {
        int m = r * T_ + t0 + wm * 32 + mt * 16 + (lane >> 4) * 4;
#pragma unroll
        for (int nt = 0; nt < 4; ++nt) {
            int col = N0 + wn * 64 + nt * 16 + l15;
            float bv = bias[col];
#pragma unroll
            for (int rg = 0; rg < 4; ++rg) {
                uint v = f2bf(acc[mt][nt][rg] + bv);
                uint pv = (uint)__shfl_xor((int)v, 1);
                if (!(lane & 1))
                    *(uint*)&xout[(long)(m + rg) * G4 + col] = v | (pv << 16);
            }
        }
    }
}

// ---------------------------------------------------------------------------
// K2 v11: v8 structure VERBATIM (128 blocks x 256 thr, agent-scope medium,
// measured 3.55 us/step) with ONE change: DETECTION PROTOCOL.
//   v8 reload-all data-polling = 128 blk x 32KB per ~800cy pass ≈ 12.6 TB/s
//   of sustained fabric traffic at the coherence point — self-contention.
//   v11: per-group arrival counter. Producer: 8B h-store (relaxed agent) ->
//   release fence (per-wave vmcnt drain; stores at IC) -> lane0 fetch_add on
//   cnt[grp][t+1]. Consumer: spin on ONE 4B counter (wave-coalesced +
//   s_sleep backoff) until ==64, then fetch h in a single guaranteed pass.
//   Ordering: cnt==64 observed at IC => all 64 waves' release-fences done =>
//   h data at IC => relaxed-agent loads (served at IC) see it.
//   Sentinels no longer needed -> 33MB 0xFF memset deleted.
// ---------------------------------------------------------------------------
__global__ __launch_bounds__(256) void k_recur(
    const ushort* __restrict__ xf, const ushort* __restrict__ xb,
    ushort* __restrict__ hfB, ushort* __restrict__ hbB,
    const ushort* __restrict__ WhhBf, const ushort* __restrict__ WhhBb,
    const float* __restrict__ s1_c0, const float* __restrict__ s2_c0,
    unsigned int* __restrict__ cnt)
{
    const int bx = blockIdx.x;
    const int s  = bx >> 6;          // stream: 0 fwd, 1 bwd
    const int rb = (bx >> 4) & 3;    // row block of 32
    const int jb = bx & 15;          // j block of 32
    const int grp = bx >> 4;         // (s,rb) group id, 0..7
    const int r0 = rb * 32, j0 = jb * 32;

    const ushort* xW  = s ? xb : xf;
    const ushort* Whh = s ? WhhBb : WhhBf;
    ushort* hB = s ? hbB : hfB;

    const int tid = threadIdx.x;
    const int lane = tid & 63;
    const int g = tid >> 6;          // wave = gate (i,f,g,o)
    const int l15 = lane & 15, q8 = (lane >> 4) * 8;

    __shared__ __align__(16) ushort As[32][520];   // 32 rows x 512 k, swizzled chunks
    __shared__ float Gs[4][32][33];                // gate pre-acts 32 x 32

    // Whh fragments resident in registers: wave g, 32 cols (2 n-tiles), K=512
    bf16x8 bfr[2][16];
#pragma unroll
    for (int nt = 0; nt < 2; ++nt) {
        const ushort* brow = &Whh[((long)g * H_ + j0 + nt * 16 + l15) * H_];
#pragma unroll
        for (int ks = 0; ks < 16; ++ks)
            bfr[nt][ks] = *(const bf16x8*)&brow[ks * 32 + q8];
    }

    // cell ownership: thread -> (row rr, 4 cols at jj)
    const int rr = tid >> 3, jj = (tid & 7) * 4;
    const int rg_ = r0 + rr;
    const int rl  = (rg_ < B_) ? rg_ : rg_ - B_;
    const float* c0p = (rg_ < B_) ? s1_c0 : s2_c0;   // [2][B][H]
    float cst[4];
#pragma unroll
    for (int cc = 0; cc < 4; ++cc)
        cst[cc] = c0p[(long)s * B_ * H_ + (long)rl * H_ + j0 + jj + cc];

    // A staging: thread -> (row arow, chunk aseg); chunk placed at (aseg+arow)&7
    const int arow = tid >> 3, aseg = tid & 7;
    const int swz = ((aseg + arow) & 7) * 8;

    for (int t = 0; t < T_; ++t) {
        // xW gate pre-activations (4 cols x 4 gates) — issued before the
        // counter wait so their latency hides under it
        uint2 xw[4];
        const long xbase = ((long)rg_ * T_ + t) * G4 + j0 + jj;
#pragma unroll
        for (int gg = 0; gg < 4; ++gg)
            xw[gg] = *(const uint2*)&xW[xbase + gg * H_];

        // wait for all 64 producer-waves of this group to publish h(t).
        // (t=0: slot 0 written by P0 kernel — visible across launch boundary)
        if (t) {
            const unsigned int* cp = &cnt[grp * TS + t];
            while (__hip_atomic_load(cp, __ATOMIC_RELAXED,
                                     __HIP_MEMORY_SCOPE_AGENT) < 64u)
                __builtin_amdgcn_s_sleep(1);
        }

        // h(t): single-pass fetch (guaranteed present at coherence point)
        const ushort* hrow = &hB[((long)(r0 + arow) * TS + t) * H_ + aseg * 8];
        unsigned long long hv[16];
#pragma unroll
        for (int i = 0; i < 16; ++i) {
            const unsigned long long* p8 =
                (const unsigned long long*)(hrow + (i >> 1) * 64 + (i & 1) * 4);
            hv[i] = __hip_atomic_load(p8, __ATOMIC_RELAXED,
                                      __HIP_MEMORY_SCOPE_AGENT);
        }

#pragma unroll
        for (int sl = 0; sl < 8; ++sl) {
            uint4 av;
            av.x = (uint)hv[2 * sl];       av.y = (uint)(hv[2 * sl] >> 32);
            av.z = (uint)hv[2 * sl + 1];   av.w = (uint)(hv[2 * sl + 1] >> 32);
            *(uint4*)&As[arow][sl * 64 + swz] = av;
        }
        __syncthreads();

        f32x4 acc[2][2] = {};   // [mtile][ntile]
#pragma unroll
        for (int ks = 0; ks < 16; ++ks) {
            const int e  = ks * 32 + q8;
            const int sl = e >> 6;
            const int c  = (e >> 3) & 7;
            bf16x8 a0 = *(const bf16x8*)&As[l15][sl * 64 + (((c + l15) & 7) << 3)];
            bf16x8 a1 = *(const bf16x8*)&As[16 + l15][sl * 64 + (((c + l15) & 7) << 3)];
            acc[0][0] = MFMA(a0, bfr[0][ks], acc[0][0]);
            acc[0][1] = MFMA(a0, bfr[1][ks], acc[0][1]);
            acc[1][0] = MFMA(a1, bfr[0][ks], acc[1][0]);
            acc[1][1] = MFMA(a1, bfr[1][ks], acc[1][1]);
        }

        // publish gate pre-acts (C layout: col=lane&15, row=(lane>>4)*4+rg)
#pragma unroll
        for (int mt = 0; mt < 2; ++mt)
#pragma unroll
            for (int nt = 0; nt < 2; ++nt)
#pragma unroll
                for (int rg2 = 0; rg2 < 4; ++rg2)
                    Gs[g][mt * 16 + (lane >> 4) * 4 + rg2][nt * 16 + l15] =
                        acc[mt][nt][rg2];
        __syncthreads();

        // fused cell update for 4 cols
        ushort hp[4];
#pragma unroll
        for (int cc = 0; cc < 4; ++cc) {
            uint xv0 = (cc < 2) ? xw[0].x : xw[0].y;
            uint xv1 = (cc < 2) ? xw[1].x : xw[1].y;
            uint xv2 = (cc < 2) ? xw[2].x : xw[2].y;
            uint xv3 = (cc < 2) ? xw[3].x : xw[3].y;
            int sh = (cc & 1) * 16;
            float gi = Gs[0][rr][jj + cc] + bf2f((ushort)(xv0 >> sh));
            float gf = Gs[1][rr][jj + cc] + bf2f((ushort)(xv1 >> sh));
            float gg = Gs[2][rr][jj + cc] + bf2f((ushort)(xv2 >> sh));
            float go = Gs[3][rr][jj + cc] + bf2f((ushort)(xv3 >> sh));
            cst[cc] = fsig(gf) * cst[cc] + fsig(gi) * ftanh(gg);
            hp[cc] = f2bf(fsig(go) * ftanh(cst[cc]));
        }
        unsigned long long pk = (unsigned long long)hp[0]
                              | ((unsigned long long)hp[1] << 16)
                              | ((unsigned long long)hp[2] << 32)
                              | ((unsigned long long)hp[3] << 48);
        __hip_atomic_store(
            (unsigned long long*)&hB[((long)rg_ * TS + t + 1) * H_ + j0 + jj],
            pk, __ATOMIC_RELAXED, __HIP_MEMORY_SCOPE_AGENT);

        // publish arrival: per-wave release (drains this wave's stores to the
        // coherence point), then one add per wave. 16 blocks x 4 waves = 64.
        __builtin_amdgcn_fence(__ATOMIC_RELEASE, "agent");
        if (lane == 0)
            __hip_atomic_fetch_add(&cnt[grp * TS + t + 1], 1u,
                                   __ATOMIC_RELAXED, __HIP_MEMORY_SCOPE_AGENT);
    }
}

// ---------------------------------------------------------------------------
// K3a: U[m,c] = tanh(Hout[m,:] @ S1W^T) via bf16 MFMA (unchanged).
// ---------------------------------------------------------------------------
__global__ __launch_bounds__(256) void k_attn_mfma(
    const ushort* __restrict__ hfB, const ushort* __restrict__ hbB,
    const int* __restrict__ l1, const int* __restrict__ l2,
    const ushort* __restrict__ S1WB, float* __restrict__ U)
{
    const int r  = blockIdx.y >> 1;
    const int t0 = (blockIdx.y & 1) * 64;
    const int N0 = blockIdx.x * 64;
    const int L  = (r < B_) ? l1[r] : l2[r - B_];
    if (L <= t0) return;

    const int tid = threadIdx.x;
    const int lane = tid & 63, w = tid >> 6;
    const int wm = w & 1, wn = w >> 1;
    const int l15 = lane & 15, q8 = (lane >> 4) * 8;

    __shared__ __align__(16) ushort As[64][72];
    __shared__ __align__(16) ushort Bs[64][72];

    f32x4 acc[2][2] = {};

    for (int k0 = 0; k0 < 2 * H_; k0 += 64) {
#pragma unroll
        for (int p = 0; p < 2; ++p) {   // A: 64 rows x 64 k
            int u = tid + p * 256;
            int row = u >> 3, seg = u & 7;
            int tpos = t0 + row;
            int k = k0 + seg * 8;
            long idx;
            const ushort* src;
            if (k0 < H_) {
                src = hfB; idx = ((long)r * TS + tpos + 1) * H_ + k;
            } else {
                int tt = (tpos < L) ? (L - 1 - tpos) : tpos;
                src = hbB; idx = ((long)r * TS + tt + 1) * H_ + (k - H_);
            }
            *(uint4*)&As[row][seg * 8] = *(const uint4*)&src[idx];
        }
#pragma unroll
        for (int p = 0; p < 2; ++p) {   // B: 64 cols x 64 k
            int u = tid + p * 256;
            int row = u >> 3, seg = u & 7;
            *(uint4*)&Bs[row][seg * 8] =
                *(const uint4*)&S1WB[(long)(N0 + row) * (2 * H_) + k0 + seg * 8];
        }
        __syncthreads();
#pragma unroll
        for (int ks = 0; ks < 2; ++ks) {
            bf16x8 a0 = *(const bf16x8*)&As[wm * 32 + l15][ks * 32 + q8];
            bf16x8 a1 = *(const bf16x8*)&As[wm * 32 + 16 + l15][ks * 32 + q8];
            bf16x8 b0 = *(const bf16x8*)&Bs[wn * 32 + l15][ks * 32 + q8];
            bf16x8 b1 = *(const bf16x8*)&Bs[wn * 32 + 16 + l15][ks * 32 + q8];
            acc[0][0] = MFMA(a0, b0, acc[0][0]);
            acc[0][1] = MFMA(a0, b1, acc[0][1]);
            acc[1][0] = MFMA(a1, b0, acc[1][0]);
            acc[1][1] = MFMA(a1, b1, acc[1][1]);
        }
        __syncthreads();
    }
#pragma unroll
    for (int mt = 0; mt < 2; ++mt) {
        int m = r * T_ + t0 + wm * 32 + mt * 16 + (lane >> 4) * 4;
#pragma unroll
        for (int nt = 0; nt < 2; ++nt) {
            int col = N0 + wn * 32 + nt * 16 + l15;
#pragma unroll
            for (int rg = 0; rg < 4; ++rg)
                U[(long)(m + rg) * C_ + col] = ftanh(acc[mt][nt][rg]);
        }
    }
}

// ---------------------------------------------------------------------------
// K3b: scores = U@S2W, masked softmax, pooled = attn @ Hout (unchanged).
// ---------------------------------------------------------------------------
__global__ __launch_bounds__(256) void k_attn_pool(
    const ushort* __restrict__ hfB, const ushort* __restrict__ hbB,
    const float* __restrict__ U, const float* __restrict__ S2W,
    const int* __restrict__ l1, const int* __restrict__ l2,
    float* __restrict__ pooled)
{
    const int r = blockIdx.x;
    const int L = (r < B_) ? l1[r] : l2[r - B_];
    const int tid = threadIdx.x;
    const int lane = tid & 63, w = tid >> 6;

    __shared__ float att[T_];

    for (int tt = w; tt < T_; tt += 4) {
        float p = 0.0f;
        if (tt < L) {
            const float* u = &U[(long)(r * T_ + tt) * C_];
            p = u[lane] * S2W[lane] + u[lane + 64] * S2W[lane + 64]
              + u[lane + 128] * S2W[lane + 128] + u[lane + 192] * S2W[lane + 192];
            for (int off = 32; off; off >>= 1) p += __shfl_down(p, off);
        }
        if (lane == 0) att[tt] = p;
    }
    __syncthreads();

    float mx = -1e30f;
    for (int tt = 0; tt < L; ++tt) mx = fmaxf(mx, att[tt]);
    __syncthreads();
    if (tid < T_) att[tid] = (tid < L) ? __expf(att[tid] - mx) : 0.0f;
    __syncthreads();
    float sum = 0.0f;
    for (int tt = 0; tt < L; ++tt) sum += att[tt];
    float inv = 1.0f / sum;

    for (int p = tid; p < 512; p += 256) {
        float a0 = 0.0f, a1 = 0.0f;
        if (p < 256) {
            int d = p * 2;
            for (int tt = 0; tt < L; ++tt) {
                uint hv = *(const uint*)&hfB[((long)r * TS + tt + 1) * H_ + d];
                a0 += att[tt] * bf2f((ushort)(hv & 0xffff));
                a1 += att[tt] * bf2f((ushort)(hv >> 16));
            }
            pooled[(long)r * (2 * H_) + d]     = a0 * inv;
            pooled[(long)r * (2 * H_) + d + 1] = a1 * inv;
        } else {
            int d = (p - 256) * 2;
            for (int tt = 0; tt < L; ++tt) {
                uint hv = *(const uint*)&hbB[((long)r * TS + (L - tt)) * H_ + d];
                a0 += att[tt] * bf2f((ushort)(hv & 0xffff));
                a1 += att[tt] * bf2f((ushort)(hv >> 16));
            }
            pooled[(long)r * (2 * H_) + H_ + d]     = a0 * inv;
            pooled[(long)r * (2 * H_) + H_ + d + 1] = a1 * inv;
        }
    }
}

// ---------------------------------------------------------------------------
// K4a: om[b][mm] = merged[b] . mlpW[mm] + mlpb[mm] (unchanged).
// ---------------------------------------------------------------------------
__global__ __launch_bounds__(256) void k_mlp1(
    const float* __restrict__ pooled,
    const float* __restrict__ mlpW, const float* __restrict__ mlpb,
    float* __restrict__ om)
{
    const int mg = blockIdx.x;      // 0..7
    const int b  = blockIdx.y;      // 0..63
    const int tid = threadIdx.x;
    const int lane = tid & 63, w = tid >> 6;

    __shared__ __align__(16) float sm[2048];

#pragma unroll
    for (int it = 0; it < 8; ++it) {
        int d = tid + it * 256;
        float v;
        if (d < 1024) {
            v = pooled[(long)b * 1024 + d] + pooled[(long)(B_ + b) * 1024 + d];
        } else {
            int dd = d - 1024;
            float x = pooled[(long)b * 1024 + dd] - pooled[(long)(B_ + b) * 1024 + dd];
            v = x * x;
        }
        sm[d] = v;
    }
    __syncthreads();

    for (int i = 0; i < 16; ++i) {
        int mm = mg * 64 + w * 16 + i;
        const float* wrow = &mlpW[(long)mm * 2048];
        float ax = 0.f, ay = 0.f, az = 0.f, aw = 0.f;
#pragma unroll
        for (int it = 0; it < 8; ++it) {
            int k = it * 256 + lane * 4;
            float4 wv = *(const float4*)&wrow[k];
            float4 sv = *(const float4*)&sm[k];
            ax += wv.x * sv.x; ay += wv.y * sv.y;
            az += wv.z * sv.z; aw += wv.w * sv.w;
        }
        float ssum = (ax + ay) + (az + aw);
        for (int off = 32; off; off >>= 1) ssum += __shfl_down(ssum, off);
        if (lane == 0) om[(long)b * M_ + mm] = ssum + mlpb[mm];
    }
}

// K4b: out[b] = sigmoid(om[b] . outW + outb)   (CLS = 1)
__global__ __launch_bounds__(256) void k_final(
    const float* __restrict__ om,
    const float* __restrict__ outW, const float* __restrict__ outb,
    float* __restrict__ out)
{
    const int b = blockIdx.x;
    const int tid = threadIdx.x;
    __shared__ float red[256];
    float p = om[(long)b * M_ + tid] * outW[tid]
            + om[(long)b * M_ + 256 + tid] * outW[256 + tid];
    red[tid] = p;
    __syncthreads();
    for (int off = 128; off > 0; off >>= 1) {
        if (tid < off) red[tid] += red[tid + off];
        __syncthreads();
    }
    if (tid == 0) out[b] = 1.0f / (1.0f + __expf(-(red[0] + outb[0])));
}

// ---------------------------------------------------------------------------
extern "C" void kernel_launch(void* const* d_in, const int* in_sizes, int n_in,
                              void* d_out, int out_size, void* d_ws, size_t ws_size,
                              hipStream_t stream)
{
    const int*   s1    = (const int*)d_in[0];
    const int*   s2    = (const int*)d_in[1];
    const int*   l1    = (const int*)d_in[2];
    const int*   l2    = (const int*)d_in[3];
    const float* s1_h0 = (const float*)d_in[4];
    const float* s1_c0 = (const float*)d_in[5];
    const float* s2_h0 = (const float*)d_in[6];
    const float* s2_c0 = (const float*)d_in[7];
    const float* emb   = (const float*)d_in[8];
    const float* Wih_f = (const float*)d_in[9];
    const float* Whh_f = (const float*)d_in[10];
    const float* b_f   = (const float*)d_in[11];
    const float* Wih_b = (const float*)d_in[12];
    const float* Whh_b = (const float*)d_in[13];
    const float* b_b   = (const float*)d_in[14];
    const float* S1W   = (const float*)d_in[15];
    const float* S2W   = (const float*)d_in[16];
    const float* mlpW  = (const float*)d_in[17];
    const float* mlpb  = (const float*)d_in[18];
    const float* outW  = (const float*)d_in[19];
    const float* outb  = (const float*)d_in[20];
    float* out = (float*)d_out;

    // Workspace carve (all 16B-aligned)
    ushort* p16 = (ushort*)d_ws;
    ushort* embB  = p16;  p16 += (long)32000 * EP;
    ushort* WihBf = p16;  p16 += (long)G4 * EP;
    ushort* WihBb = p16;  p16 += (long)G4 * EP;
    ushort* WhhBf = p16;  p16 += (long)G4 * H_;
    ushort* WhhBb = p16;  p16 += (long)G4 * H_;
    ushort* S1WB  = p16;  p16 += (long)C_ * 2 * H_;
    ushort* xf    = p16;  p16 += (long)R_ * T_ * G4;
    ushort* xb    = p16;  p16 += (long)R_ * T_ * G4;
    ushort* hfB   = p16;  p16 += (long)R_ * TS * H_;
    ushort* hbB   = p16;  p16 += (long)R_ * TS * H_;
    unsigned int* cnt = (unsigned int*)p16;  p16 += 8 * TS * 2;  // 8 groups x TS u32
    float* pf = (float*)p16;
    float* U      = pf;   pf += (long)R_ * T_ * C_;
    float* pooled = pf;   pf += (long)R_ * 2 * H_;
    float* om     = pf;   pf += (long)B_ * M_;

    // zero the arrival counters (the only init the dataflow sync needs now;
    // the 33MB 0xFF sentinel memset is gone — counters replace sentinels)
    hipMemsetAsync(cnt, 0, (size_t)8 * TS * sizeof(unsigned int), stream);

    // P0: fused weight conversion + h0 init (one launch)
    k_cvt_all<<<40576, 256, 0, stream>>>(emb, Wih_f, Wih_b, Whh_f, Whh_b, S1W,
                                         s1_h0, s2_h0,
                                         embB, WihBf, WihBb, WhhBf, WhhBb, S1WB,
                                         hfB, hbB);

    // K1: input GEMM
    k_embed_mfma<<<dim3(16, 256, 2), 256, 0, stream>>>(
        s1, s2, l1, l2, embB, WihBf, WihBb, b_f, b_b, xf, xb);

    // K2: full recurrence in ONE persistent launch (counter dataflow sync)
    k_recur<<<NB, 256, 0, stream>>>(xf, xb, hfB, hbB, WhhBf, WhhBb,
                                    s1_c0, s2_c0, cnt);

    // K3: attention pooling
    k_attn_mfma<<<dim3(4, 256), 256, 0, stream>>>(hfB, hbB, l1, l2, S1WB, U);
    k_attn_pool<<<R_, 256, 0, stream>>>(hfB, hbB, U, S2W, l1, l2, pooled);

    // K4: MLP head
    k_mlp1<<<dim3(8, B_), 256, 0, stream>>>(pooled, mlpW, mlpb, om);
    k_final<<<B_, 256, 0, stream>>>(om, outW, outb, out);
}

// Round 4
// 934.128 us; speedup vs baseline: 2.2065x; 2.2065x over previous
//
#include <hip/hip_runtime.h>
#include <hip/hip_bf16.h>

// Problem constants (fixed by the reference)
#define B_  64
#define T_  128
#define E_  300
#define EP  320     // E padded to multiple of 32 for MFMA K-loop
#define H_  512
#define G4  2048    // 4*H
#define R_  128     // 2*B (s1+s2 batched; shared LSTM weights)
#define C_  256
#define M_  512
#define TS  (T_ + 1)  // h time slots: slot 0 = h0, slot t+1 = h(t)
#define NB  128     // persistent-kernel grid: 2 streams x 4 rowblocks x 16 jblocks
#define SENT 0xFFFFFFFFFFFFFFFFULL   // 4x bf16 NaN — unreachable by real h

typedef short bf16x8 __attribute__((ext_vector_type(8)));
typedef float f32x4  __attribute__((ext_vector_type(4)));
#define MFMA(a, b, c) __builtin_amdgcn_mfma_f32_16x16x32_bf16((a), (b), (c), 0, 0, 0)

__device__ __forceinline__ float fsig(float x) { return 1.0f / (1.0f + __expf(-x)); }
__device__ __forceinline__ float ftanh(float x) {
    float a = fminf(fabsf(x), 15.0f);
    float e = __expf(2.0f * a);
    return copysignf((e - 1.0f) / (e + 1.0f), x);
}
__device__ __forceinline__ ushort f2bf(float f) {
    __hip_bfloat16 h = __float2bfloat16(f);
    return *reinterpret_cast<ushort*>(&h);
}
__device__ __forceinline__ float bf2f(ushort u) {
    __hip_bfloat16 h = *reinterpret_cast<__hip_bfloat16*>(&u);
    return __bfloat162float(h);
}

// ---------------------------------------------------------------------------
// P0: fused f32 -> bf16 conversion for ALL weight tensors + h0/sentinel init.
// Blocks [0,40448): weight regions (K-padding zeros in [sk,dk)).
// Blocks [40448, 40576): h slot-0 init from h0 inputs (after 0xFF memset).
// (round-0 measured-best version, verbatim)
// ---------------------------------------------------------------------------
__global__ __launch_bounds__(256) void k_cvt_all(
    const float* __restrict__ emb,
    const float* __restrict__ Wih_f, const float* __restrict__ Wih_b,
    const float* __restrict__ Whh_f, const float* __restrict__ Whh_b,
    const float* __restrict__ S1W,
    const float* __restrict__ s1_h0, const float* __restrict__ s2_h0,
    ushort* __restrict__ embB,
    ushort* __restrict__ WihBf, ushort* __restrict__ WihBb,
    ushort* __restrict__ WhhBf, ushort* __restrict__ WhhBb,
    ushort* __restrict__ S1WB,
    ushort* __restrict__ hfB, ushort* __restrict__ hbB)
{
    int b = blockIdx.x;
    if (b >= 40448) {   // h0 init role
        const int r = b - 40448;                     // 0..127
        const int rl = (r < B_) ? r : r - B_;
        const float* h0 = (r < B_) ? s1_h0 : s2_h0;  // [2][B][H]
        for (int j = threadIdx.x; j < H_; j += 256) {
            hfB[(long)r * TS * H_ + j] = f2bf(h0[(long)0 * B_ * H_ + (long)rl * H_ + j]);
            hbB[(long)r * TS * H_ + j] = f2bf(h0[(long)1 * B_ * H_ + (long)rl * H_ + j]);
        }
        return;
    }
    const float* src; ushort* dst; int r, sk, dk;
    if (b < 32000)      { src = emb;   dst = embB;  r = b;          sk = E_;    dk = EP; }
    else if (b < 34048) { src = Wih_f; dst = WihBf; r = b - 32000;  sk = E_;    dk = EP; }
    else if (b < 36096) { src = Wih_b; dst = WihBb; r = b - 34048;  sk = E_;    dk = EP; }
    else if (b < 38144) { src = Whh_f; dst = WhhBf; r = b - 36096;  sk = H_;    dk = H_; }
    else if (b < 40192) { src = Whh_b; dst = WhhBb; r = b - 38144;  sk = H_;    dk = H_; }
    else                { src = S1W;   dst = S1WB;  r = b - 40192;  sk = 2*H_;  dk = 2*H_; }
    for (int c = threadIdx.x; c < dk; c += 256)
        dst[(long)r * dk + c] = (c < sk) ? f2bf(src[(long)r * sk + c]) : (ushort)0;
}

// ---------------------------------------------------------------------------
// K1: embedding gather + input GEMM via bf16 MFMA (round-0 verbatim).
// ---------------------------------------------------------------------------
__global__ __launch_bounds__(256) void k_embed_mfma(
    const int* __restrict__ s1, const int* __restrict__ s2,
    const int* __restrict__ l1, const int* __restrict__ l2,
    const ushort* __restrict__ embB,
    const ushort* __restrict__ WihBf, const ushort* __restrict__ WihBb,
    const float* __restrict__ b_f, const float* __restrict__ b_b,
    ushort* __restrict__ xf, ushort* __restrict__ xb)
{
    const int dir = blockIdx.z;
    const int r   = blockIdx.y >> 1;
    const int t0  = (blockIdx.y & 1) * 64;
    const int N0  = blockIdx.x * 128;
    const int L   = (r < B_) ? l1[r] : l2[r - B_];
    if (L <= t0) return;

    const int tid = threadIdx.x;
    const int lane = tid & 63, w = tid >> 6;
    const int wm = w & 1, wn = w >> 1;
    const int l15 = lane & 15, q8 = (lane >> 4) * 8;

    __shared__ int toks[64];
    __shared__ __align__(16) ushort As[64][40];
    __shared__ __align__(16) ushort Bs[128][40];

    if (tid < 64) {
        int t  = t0 + tid;
        int tt = dir ? ((t < L) ? (L - 1 - t) : t) : t;
        toks[tid] = (r < B_) ? s1[r * T_ + tt] : s2[(r - B_) * T_ + tt];
    }
    __syncthreads();

    const ushort* Wih  = dir ? WihBb : WihBf;
    const float*  bias = dir ? b_b : b_f;

    f32x4 acc[2][4] = {};

    for (int k0 = 0; k0 < EP; k0 += 32) {
        {   // A: 64 rows x 32 k
            int row = tid >> 2, seg = tid & 3;
            *(uint4*)&As[row][seg * 8] =
                *(const uint4*)&embB[(long)toks[row] * EP + k0 + seg * 8];
        }
#pragma unroll
        for (int p = 0; p < 2; ++p) {   // B: 128 cols x 32 k
            int u = tid + p * 256;
            int row = u >> 2, seg = u & 3;
            *(uint4*)&Bs[row][seg * 8] =
                *(const uint4*)&Wih[(long)(N0 + row) * EP + k0 + seg * 8];
        }
        __syncthreads();
        bf16x8 af[2], bfr[4];
#pragma unroll
        for (int mt = 0; mt < 2; ++mt)
            af[mt] = *(const bf16x8*)&As[wm * 32 + mt * 16 + l15][q8];
#pragma unroll
        for (int nt = 0; nt < 4; ++nt)
            bfr[nt] = *(const bf16x8*)&Bs[wn * 64 + nt * 16 + l15][q8];
#pragma unroll
        for (int mt = 0; mt < 2; ++mt)
#pragma unroll
            for (int nt = 0; nt < 4; ++nt)
                acc[mt][nt] = MFMA(af[mt], bfr[nt], acc[mt][nt]);
        __syncthreads();
    }

    ushort* xout = dir ? xb : xf;
#pragma unroll
    for (int mt = 0; mt < 2; ++mt) {
        int m = r * T_ + t0 + wm * 32 + mt * 16 + (lane >> 4) * 4;
#pragma unroll
        for (int nt = 0; nt < 4; ++nt) {
            int col = N0 + wn * 64 + nt * 16 + l15;
            float bv = bias[col];
#pragma unroll
            for (int rg = 0; rg < 4; ++rg) {
                uint v = f2bf(acc[mt][nt][rg] + bv);
                uint pv = (uint)__shfl_xor((int)v, 1);
                if (!(lane & 1))
                    *(uint*)&xout[(long)(m + rg) * G4 + col] = v | (pv << 16);
            }
        }
    }
}

// ---------------------------------------------------------------------------
// K2 v12: v8 VERBATIM structure (128 blocks x 256 thr, sentinel data-poll,
// relaxed agent atomics, NO fences — the only protocol that works) with TWO
// surgical tweaks to the poll loop ONLY:
//   (a) accept-once: chunks that passed the sentinel check are not re-loaded
//       on subsequent passes (round-1 proved this cuts FETCH 2.6x; here it
//       is isolated from the structural changes that masked it).
//   (b) s_sleep(2) backoff between failed passes (~128cy), cutting the
//       sustained agent-load poll traffic at the coherence point.
//   Everything else — grid, wave roles, LDS layout, MFMA loop, cell update,
//   h store — is byte-identical to the 456us/3.55us-per-step v8.
// ---------------------------------------------------------------------------
__global__ __launch_bounds__(256) void k_recur(
    const ushort* __restrict__ xf, const ushort* __restrict__ xb,
    ushort* __restrict__ hfB, ushort* __restrict__ hbB,
    const ushort* __restrict__ WhhBf, const ushort* __restrict__ WhhBb,
    const float* __restrict__ s1_c0, const float* __restrict__ s2_c0)
{
    const int bx = blockIdx.x;
    const int s  = bx >> 6;          // stream: 0 fwd, 1 bwd
    const int rb = (bx >> 4) & 3;    // row block of 32
    const int jb = bx & 15;          // j block of 32
    const int r0 = rb * 32, j0 = jb * 32;

    const ushort* xW  = s ? xb : xf;
    const ushort* Whh = s ? WhhBb : WhhBf;
    ushort* hB = s ? hbB : hfB;

    const int tid = threadIdx.x;
    const int lane = tid & 63;
    const int g = tid >> 6;          // wave = gate (i,f,g,o)
    const int l15 = lane & 15, q8 = (lane >> 4) * 8;

    __shared__ __align__(16) ushort As[32][520];   // 32 rows x 512 k, swizzled chunks
    __shared__ float Gs[4][32][33];                // gate pre-acts 32 x 32

    // Whh fragments resident in registers: wave g, 32 cols (2 n-tiles), K=512
    bf16x8 bfr[2][16];
#pragma unroll
    for (int nt = 0; nt < 2; ++nt) {
        const ushort* brow = &Whh[((long)g * H_ + j0 + nt * 16 + l15) * H_];
#pragma unroll
        for (int ks = 0; ks < 16; ++ks)
            bfr[nt][ks] = *(const bf16x8*)&brow[ks * 32 + q8];
    }

    // cell ownership: thread -> (row rr, 4 cols at jj)
    const int rr = tid >> 3, jj = (tid & 7) * 4;
    const int rg_ = r0 + rr;
    const int rl  = (rg_ < B_) ? rg_ : rg_ - B_;
    const float* c0p = (rg_ < B_) ? s1_c0 : s2_c0;   // [2][B][H]
    float cst[4];
#pragma unroll
    for (int cc = 0; cc < 4; ++cc)
        cst[cc] = c0p[(long)s * B_ * H_ + (long)rl * H_ + j0 + jj + cc];

    // A staging: thread -> (row arow, chunk aseg); chunk placed at (aseg+arow)&7
    const int arow = tid >> 3, aseg = tid & 7;
    const int swz = ((aseg + arow) & 7) * 8;

    for (int t = 0; t < T_; ++t) {
        // xW gate pre-activations (4 cols x 4 gates) — issued before the
        // h poll so their latency hides under the wait
        uint2 xw[4];
        const long xbase = ((long)rg_ * T_ + t) * G4 + j0 + jj;
#pragma unroll
        for (int gg = 0; gg < 4; ++gg)
            xw[gg] = *(const uint2*)&xW[xbase + gg * H_];

        // h(t): poll the data itself. 16 x 8B chunks; ACCEPT-ONCE + backoff.
        const ushort* hrow = &hB[((long)(r0 + arow) * TS + t) * H_ + aseg * 8];
        unsigned long long hv[16];
        unsigned int pend = 0xFFFFu;
        do {
            unsigned long long tmp[16];
#pragma unroll
            for (int i = 0; i < 16; ++i)
                if (pend & (1u << i)) {
                    const unsigned long long* p8 =
                        (const unsigned long long*)(hrow + (i >> 1) * 64 + (i & 1) * 4);
                    tmp[i] = __hip_atomic_load(p8, __ATOMIC_RELAXED,
                                               __HIP_MEMORY_SCOPE_AGENT);
                }
#pragma unroll
            for (int i = 0; i < 16; ++i)
                if ((pend & (1u << i)) && tmp[i] != SENT) {
                    hv[i] = tmp[i];
                    pend &= ~(1u << i);
                }
            if (pend) __builtin_amdgcn_s_sleep(2);
        } while (pend);

#pragma unroll
        for (int sl = 0; sl < 8; ++sl) {
            uint4 av;
            av.x = (uint)hv[2 * sl];       av.y = (uint)(hv[2 * sl] >> 32);
            av.z = (uint)hv[2 * sl + 1];   av.w = (uint)(hv[2 * sl + 1] >> 32);
            *(uint4*)&As[arow][sl * 64 + swz] = av;
        }
        __syncthreads();

        f32x4 acc[2][2] = {};   // [mtile][ntile]
#pragma unroll
        for (int ks = 0; ks < 16; ++ks) {
            const int e  = ks * 32 + q8;
            const int sl = e >> 6;
            const int c  = (e >> 3) & 7;
            bf16x8 a0 = *(const bf16x8*)&As[l15][sl * 64 + (((c + l15) & 7) << 3)];
            bf16x8 a1 = *(const bf16x8*)&As[16 + l15][sl * 64 + (((c + l15) & 7) << 3)];
            acc[0][0] = MFMA(a0, bfr[0][ks], acc[0][0]);
            acc[0][1] = MFMA(a0, bfr[1][ks], acc[0][1]);
            acc[1][0] = MFMA(a1, bfr[0][ks], acc[1][0]);
            acc[1][1] = MFMA(a1, bfr[1][ks], acc[1][1]);
        }

        // publish gate pre-acts (C layout: col=lane&15, row=(lane>>4)*4+rg)
#pragma unroll
        for (int mt = 0; mt < 2; ++mt)
#pragma unroll
            for (int nt = 0; nt < 2; ++nt)
#pragma unroll
                for (int rg2 = 0; rg2 < 4; ++rg2)
                    Gs[g][mt * 16 + (lane >> 4) * 4 + rg2][nt * 16 + l15] =
                        acc[mt][nt][rg2];
        __syncthreads();

        // fused cell update for 4 cols
        ushort hp[4];
#pragma unroll
        for (int cc = 0; cc < 4; ++cc) {
            uint xv0 = (cc < 2) ? xw[0].x : xw[0].y;
            uint xv1 = (cc < 2) ? xw[1].x : xw[1].y;
            uint xv2 = (cc < 2) ? xw[2].x : xw[2].y;
            uint xv3 = (cc < 2) ? xw[3].x : xw[3].y;
            int sh = (cc & 1) * 16;
            float gi = Gs[0][rr][jj + cc] + bf2f((ushort)(xv0 >> sh));
            float gf = Gs[1][rr][jj + cc] + bf2f((ushort)(xv1 >> sh));
            float gg = Gs[2][rr][jj + cc] + bf2f((ushort)(xv2 >> sh));
            float go = Gs[3][rr][jj + cc] + bf2f((ushort)(xv3 >> sh));
            cst[cc] = fsig(gf) * cst[cc] + fsig(gi) * ftanh(gg);
            hp[cc] = f2bf(fsig(go) * ftanh(cst[cc]));
        }
        unsigned long long pk = (unsigned long long)hp[0]
                              | ((unsigned long long)hp[1] << 16)
                              | ((unsigned long long)hp[2] << 32)
                              | ((unsigned long long)hp[3] << 48);
        __hip_atomic_store(
            (unsigned long long*)&hB[((long)rg_ * TS + t + 1) * H_ + j0 + jj],
            pk, __ATOMIC_RELAXED, __HIP_MEMORY_SCOPE_AGENT);
    }
}

// ---------------------------------------------------------------------------
// K3a: U[m,c] = tanh(Hout[m,:] @ S1W^T) via bf16 MFMA (unchanged).
// ---------------------------------------------------------------------------
__global__ __launch_bounds__(256) void k_attn_mfma(
    const ushort* __restrict__ hfB, const ushort* __restrict__ hbB,
    const int* __restrict__ l1, const int* __restrict__ l2,
    const ushort* __restrict__ S1WB, float* __restrict__ U)
{
    const int r  = blockIdx.y >> 1;
    const int t0 = (blockIdx.y & 1) * 64;
    const int N0 = blockIdx.x * 64;
    const int L  = (r < B_) ? l1[r] : l2[r - B_];
    if (L <= t0) return;

    const int tid = threadIdx.x;
    const int lane = tid & 63, w = tid >> 6;
    const int wm = w & 1, wn = w >> 1;
    const int l15 = lane & 15, q8 = (lane >> 4) * 8;

    __shared__ __align__(16) ushort As[64][72];
    __shared__ __align__(16) ushort Bs[64][72];

    f32x4 acc[2][2] = {};

    for (int k0 = 0; k0 < 2 * H_; k0 += 64) {
#pragma unroll
        for (int p = 0; p < 2; ++p) {   // A: 64 rows x 64 k
            int u = tid + p * 256;
            int row = u >> 3, seg = u & 7;
            int tpos = t0 + row;
            int k = k0 + seg * 8;
            long idx;
            const ushort* src;
            if (k0 < H_) {
                src = hfB; idx = ((long)r * TS + tpos + 1) * H_ + k;
            } else {
                int tt = (tpos < L) ? (L - 1 - tpos) : tpos;
                src = hbB; idx = ((long)r * TS + tt + 1) * H_ + (k - H_);
            }
            *(uint4*)&As[row][seg * 8] = *(const uint4*)&src[idx];
        }
#pragma unroll
        for (int p = 0; p < 2; ++p) {   // B: 64 cols x 64 k
            int u = tid + p * 256;
            int row = u >> 3, seg = u & 7;
            *(uint4*)&Bs[row][seg * 8] =
                *(const uint4*)&S1WB[(long)(N0 + row) * (2 * H_) + k0 + seg * 8];
        }
        __syncthreads();
#pragma unroll
        for (int ks = 0; ks < 2; ++ks) {
            bf16x8 a0 = *(const bf16x8*)&As[wm * 32 + l15][ks * 32 + q8];
            bf16x8 a1 = *(const bf16x8*)&As[wm * 32 + 16 + l15][ks * 32 + q8];
            bf16x8 b0 = *(const bf16x8*)&Bs[wn * 32 + l15][ks * 32 + q8];
            bf16x8 b1 = *(const bf16x8*)&Bs[wn * 32 + 16 + l15][ks * 32 + q8];
            acc[0][0] = MFMA(a0, b0, acc[0][0]);
            acc[0][1] = MFMA(a0, b1, acc[0][1]);
            acc[1][0] = MFMA(a1, b0, acc[1][0]);
            acc[1][1] = MFMA(a1, b1, acc[1][1]);
        }
        __syncthreads();
    }
#pragma unroll
    for (int mt = 0; mt < 2; ++mt) {
        int m = r * T_ + t0 + wm * 32 + mt * 16 + (lane >> 4) * 4;
#pragma unroll
        for (int nt = 0; nt < 2; ++nt) {
            int col = N0 + wn * 32 + nt * 16 + l15;
#pragma unroll
            for (int rg = 0; rg < 4; ++rg)
                U[(long)(m + rg) * C_ + col] = ftanh(acc[mt][nt][rg]);
        }
    }
}

// ---------------------------------------------------------------------------
// K3b: scores = U@S2W, masked softmax, pooled = attn @ Hout (unchanged).
// ---------------------------------------------------------------------------
__global__ __launch_bounds__(256) void k_attn_pool(
    const ushort* __restrict__ hfB, const ushort* __restrict__ hbB,
    const float* __restrict__ U, const float* __restrict__ S2W,
    const int* __restrict__ l1, const int* __restrict__ l2,
    float* __restrict__ pooled)
{
    const int r = blockIdx.x;
    const int L = (r < B_) ? l1[r] : l2[r - B_];
    const int tid = threadIdx.x;
    const int lane = tid & 63, w = tid >> 6;

    __shared__ float att[T_];

    for (int tt = w; tt < T_; tt += 4) {
        float p = 0.0f;
        if (tt < L) {
            const float* u = &U[(long)(r * T_ + tt) * C_];
            p = u[lane] * S2W[lane] + u[lane + 64] * S2W[lane + 64]
              + u[lane + 128] * S2W[lane + 128] + u[lane + 192] * S2W[lane + 192];
            for (int off = 32; off; off >>= 1) p += __shfl_down(p, off);
        }
        if (lane == 0) att[tt] = p;
    }
    __syncthreads();

    float mx = -1e30f;
    for (int tt = 0; tt < L; ++tt) mx = fmaxf(mx, att[tt]);
    __syncthreads();
    if (tid < T_) att[tid] = (tid < L) ? __expf(att[tid] - mx) : 0.0f;
    __syncthreads();
    float sum = 0.0f;
    for (int tt = 0; tt < L; ++tt) sum += att[tt];
    float inv = 1.0f / sum;

    for (int p = tid; p < 512; p += 256) {
        float a0 = 0.0f, a1 = 0.0f;
        if (p < 256) {
            int d = p * 2;
            for (int tt = 0; tt < L; ++tt) {
                uint hv = *(const uint*)&hfB[((long)r * TS + tt + 1) * H_ + d];
                a0 += att[tt] * bf2f((ushort)(hv & 0xffff));
                a1 += att[tt] * bf2f((ushort)(hv >> 16));
            }
            pooled[(long)r * (2 * H_) + d]     = a0 * inv;
            pooled[(long)r * (2 * H_) + d + 1] = a1 * inv;
        } else {
            int d = (p - 256) * 2;
            for (int tt = 0; tt < L; ++tt) {
                uint hv = *(const uint*)&hbB[((long)r * TS + (L - tt)) * H_ + d];
                a0 += att[tt] * bf2f((ushort)(hv & 0xffff));
                a1 += att[tt] * bf2f((ushort)(hv >> 16));
            }
            pooled[(long)r * (2 * H_) + H_ + d]     = a0 * inv;
            pooled[(long)r * (2 * H_) + H_ + d + 1] = a1 * inv;
        }
    }
}

// ---------------------------------------------------------------------------
// K4a: om[b][mm] = merged[b] . mlpW[mm] + mlpb[mm] (unchanged).
// ---------------------------------------------------------------------------
__global__ __launch_bounds__(256) void k_mlp1(
    const float* __restrict__ pooled,
    const float* __restrict__ mlpW, const float* __restrict__ mlpb,
    float* __restrict__ om)
{
    const int mg = blockIdx.x;      // 0..7
    const int b  = blockIdx.y;      // 0..63
    const int tid = threadIdx.x;
    const int lane = tid & 63, w = tid >> 6;

    __shared__ __align__(16) float sm[2048];

#pragma unroll
    for (int it = 0; it < 8; ++it) {
        int d = tid + it * 256;
        float v;
        if (d < 1024) {
            v = pooled[(long)b * 1024 + d] + pooled[(long)(B_ + b) * 1024 + d];
        } else {
            int dd = d - 1024;
            float x = pooled[(long)b * 1024 + dd] - pooled[(long)(B_ + b) * 1024 + dd];
            v = x * x;
        }
        sm[d] = v;
    }
    __syncthreads();

    for (int i = 0; i < 16; ++i) {
        int mm = mg * 64 + w * 16 + i;
        const float* wrow = &mlpW[(long)mm * 2048];
        float ax = 0.f, ay = 0.f, az = 0.f, aw = 0.f;
#pragma unroll
        for (int it = 0; it < 8; ++it) {
            int k = it * 256 + lane * 4;
            float4 wv = *(const float4*)&wrow[k];
            float4 sv = *(const float4*)&sm[k];
            ax += wv.x * sv.x; ay += wv.y * sv.y;
            az += wv.z * sv.z; aw += wv.w * sv.w;
        }
        float ssum = (ax + ay) + (az + aw);
        for (int off = 32; off; off >>= 1) ssum += __shfl_down(ssum, off);
        if (lane == 0) om[(long)b * M_ + mm] = ssum + mlpb[mm];
    }
}

// K4b: out[b] = sigmoid(om[b] . outW + outb)   (CLS = 1)
__global__ __launch_bounds__(256) void k_final(
    const float* __restrict__ om,
    const float* __restrict__ outW, const float* __restrict__ outb,
    float* __restrict__ out)
{
    const int b = blockIdx.x;
    const int tid = threadIdx.x;
    __shared__ float red[256];
    float p = om[(long)b * M_ + tid] * outW[tid]
            + om[(long)b * M_ + 256 + tid] * outW[256 + tid];
    red[tid] = p;
    __syncthreads();
    for (int off = 128; off > 0; off >>= 1) {
        if (tid < off) red[tid] += red[tid + off];
        __syncthreads();
    }
    if (tid == 0) out[b] = 1.0f / (1.0f + __expf(-(red[0] + outb[0])));
}

// ---------------------------------------------------------------------------
extern "C" void kernel_launch(void* const* d_in, const int* in_sizes, int n_in,
                              void* d_out, int out_size, void* d_ws, size_t ws_size,
                              hipStream_t stream)
{
    const int*   s1    = (const int*)d_in[0];
    const int*   s2    = (const int*)d_in[1];
    const int*   l1    = (const int*)d_in[2];
    const int*   l2    = (const int*)d_in[3];
    const float* s1_h0 = (const float*)d_in[4];
    const float* s1_c0 = (const float*)d_in[5];
    const float* s2_h0 = (const float*)d_in[6];
    const float* s2_c0 = (const float*)d_in[7];
    const float* emb   = (const float*)d_in[8];
    const float* Wih_f = (const float*)d_in[9];
    const float* Whh_f = (const float*)d_in[10];
    const float* b_f   = (const float*)d_in[11];
    const float* Wih_b = (const float*)d_in[12];
    const float* Whh_b = (const float*)d_in[13];
    const float* b_b   = (const float*)d_in[14];
    const float* S1W   = (const float*)d_in[15];
    const float* S2W   = (const float*)d_in[16];
    const float* mlpW  = (const float*)d_in[17];
    const float* mlpb  = (const float*)d_in[18];
    const float* outW  = (const float*)d_in[19];
    const float* outb  = (const float*)d_in[20];
    float* out = (float*)d_out;

    // Workspace carve (all 16B-aligned)
    ushort* p16 = (ushort*)d_ws;
    ushort* embB  = p16;  p16 += (long)32000 * EP;
    ushort* WihBf = p16;  p16 += (long)G4 * EP;
    ushort* WihBb = p16;  p16 += (long)G4 * EP;
    ushort* WhhBf = p16;  p16 += (long)G4 * H_;
    ushort* WhhBb = p16;  p16 += (long)G4 * H_;
    ushort* S1WB  = p16;  p16 += (long)C_ * 2 * H_;
    ushort* xf    = p16;  p16 += (long)R_ * T_ * G4;
    ushort* xb    = p16;  p16 += (long)R_ * T_ * G4;
    ushort* hfB   = p16;  p16 += (long)R_ * TS * H_;
    ushort* hbB   = p16;  p16 += (long)R_ * TS * H_;
    float* pf = (float*)p16;
    float* U      = pf;   pf += (long)R_ * T_ * C_;
    float* pooled = pf;   pf += (long)R_ * 2 * H_;
    float* om     = pf;   pf += (long)B_ * M_;

    // sentinel-fill h arrays (0xFF bytes -> every 8B chunk = SENT); the
    // cvt_all init-role then writes real h0 into slot 0. hfB/hbB contiguous.
    hipMemsetAsync(hfB, 0xFF, (size_t)2 * R_ * TS * H_ * sizeof(ushort), stream);

    // P0: fused weight conversion + h0 init (one launch)
    k_cvt_all<<<40576, 256, 0, stream>>>(emb, Wih_f, Wih_b, Whh_f, Whh_b, S1W,
                                         s1_h0, s2_h0,
                                         embB, WihBf, WihBb, WhhBf, WhhBb, S1WB,
                                         hfB, hbB);

    // K1: input GEMM
    k_embed_mfma<<<dim3(16, 256, 2), 256, 0, stream>>>(
        s1, s2, l1, l2, embB, WihBf, WihBb, b_f, b_b, xf, xb);

    // K2: full recurrence in ONE persistent launch (dataflow sync, v12 poll)
    k_recur<<<NB, 256, 0, stream>>>(xf, xb, hfB, hbB, WhhBf, WhhBb,
                                    s1_c0, s2_c0);

    // K3: attention pooling
    k_attn_mfma<<<dim3(4, 256), 256, 0, stream>>>(hfB, hbB, l1, l2, S1WB, U);
    k_attn_pool<<<R_, 256, 0, stream>>>(hfB, hbB, U, S2W, l1, l2, pooled);

    // K4: MLP head
    k_mlp1<<<dim3(8, B_), 256, 0, stream>>>(pooled, mlpW, mlpb, om);
    k_final<<<B_, 256, 0, stream>>>(om, outW, outb, out);
}

// Round 5
// 802.824 us; speedup vs baseline: 2.5674x; 1.1636x over previous
//
#include <hip/hip_runtime.h>
#include <hip/hip_bf16.h>

// Problem constants (fixed by the reference)
#define B_  64
#define T_  128
#define E_  300
#define EP  320     // E padded to multiple of 32 for MFMA K-loop
#define H_  512
#define G4  2048    // 4*H
#define R_  128     // 2*B (s1+s2 batched; shared LSTM weights)
#define C_  256
#define M_  512
#define TS  (T_ + 1)  // h time slots: slot 0 = h0, slot t+1 = h(t)
#define NB  128     // persistent-kernel grid: 2 streams x 4 rowblocks x 16 jblocks
#define SENT 0xFFFFFFFFFFFFFFFFULL   // 4x bf16 NaN — unreachable by real h

typedef short bf16x8 __attribute__((ext_vector_type(8)));
typedef float f32x4  __attribute__((ext_vector_type(4)));
#define MFMA(a, b, c) __builtin_amdgcn_mfma_f32_16x16x32_bf16((a), (b), (c), 0, 0, 0)

__device__ __forceinline__ float fsig(float x) { return 1.0f / (1.0f + __expf(-x)); }
__device__ __forceinline__ float ftanh(float x) {
    float a = fminf(fabsf(x), 15.0f);
    float e = __expf(2.0f * a);
    return copysignf((e - 1.0f) / (e + 1.0f), x);
}
__device__ __forceinline__ ushort f2bf(float f) {
    __hip_bfloat16 h = __float2bfloat16(f);
    return *reinterpret_cast<ushort*>(&h);
}
__device__ __forceinline__ float bf2f(ushort u) {
    __hip_bfloat16 h = *reinterpret_cast<__hip_bfloat16*>(&u);
    return __bfloat162float(h);
}

// ---------------------------------------------------------------------------
// P0: fused f32 -> bf16 conversion for ALL weight tensors + h0/sentinel init.
// (round-0 measured-best version, verbatim)
// ---------------------------------------------------------------------------
__global__ __launch_bounds__(256) void k_cvt_all(
    const float* __restrict__ emb,
    const float* __restrict__ Wih_f, const float* __restrict__ Wih_b,
    const float* __restrict__ Whh_f, const float* __restrict__ Whh_b,
    const float* __restrict__ S1W,
    const float* __restrict__ s1_h0, const float* __restrict__ s2_h0,
    ushort* __restrict__ embB,
    ushort* __restrict__ WihBf, ushort* __restrict__ WihBb,
    ushort* __restrict__ WhhBf, ushort* __restrict__ WhhBb,
    ushort* __restrict__ S1WB,
    ushort* __restrict__ hfB, ushort* __restrict__ hbB)
{
    int b = blockIdx.x;
    if (b >= 40448) {   // h0 init role
        const int r = b - 40448;                     // 0..127
        const int rl = (r < B_) ? r : r - B_;
        const float* h0 = (r < B_) ? s1_h0 : s2_h0;  // [2][B][H]
        for (int j = threadIdx.x; j < H_; j += 256) {
            hfB[(long)r * TS * H_ + j] = f2bf(h0[(long)0 * B_ * H_ + (long)rl * H_ + j]);
            hbB[(long)r * TS * H_ + j] = f2bf(h0[(long)1 * B_ * H_ + (long)rl * H_ + j]);
        }
        return;
    }
    const float* src; ushort* dst; int r, sk, dk;
    if (b < 32000)      { src = emb;   dst = embB;  r = b;          sk = E_;    dk = EP; }
    else if (b < 34048) { src = Wih_f; dst = WihBf; r = b - 32000;  sk = E_;    dk = EP; }
    else if (b < 36096) { src = Wih_b; dst = WihBb; r = b - 34048;  sk = E_;    dk = EP; }
    else if (b < 38144) { src = Whh_f; dst = WhhBf; r = b - 36096;  sk = H_;    dk = H_; }
    else if (b < 40192) { src = Whh_b; dst = WhhBb; r = b - 38144;  sk = H_;    dk = H_; }
    else                { src = S1W;   dst = S1WB;  r = b - 40192;  sk = 2*H_;  dk = 2*H_; }
    for (int c = threadIdx.x; c < dk; c += 256)
        dst[(long)r * dk + c] = (c < sk) ? f2bf(src[(long)r * sk + c]) : (ushort)0;
}

// ---------------------------------------------------------------------------
// K1 v2: embedding gather + input GEMM via bf16 MFMA.
// Tile widened 64x128 -> 64x256, BK 32 -> 64: halves barrier count (20->10),
// 4x fewer blocks, 160 MFMA/wave. L<=t0 early-exit preserved.
// Epilogue pairing via shfl_xor(1) unchanged (HW-validated).
// ---------------------------------------------------------------------------
__global__ __launch_bounds__(256) void k_embed_mfma(
    const int* __restrict__ s1, const int* __restrict__ s2,
    const int* __restrict__ l1, const int* __restrict__ l2,
    const ushort* __restrict__ embB,
    const ushort* __restrict__ WihBf, const ushort* __restrict__ WihBb,
    const float* __restrict__ b_f, const float* __restrict__ b_b,
    ushort* __restrict__ xf, ushort* __restrict__ xb)
{
    const int dir = blockIdx.z;
    const int r   = blockIdx.y >> 1;
    const int t0  = (blockIdx.y & 1) * 64;
    const int N0  = blockIdx.x * 256;
    const int L   = (r < B_) ? l1[r] : l2[r - B_];
    if (L <= t0) return;

    const int tid = threadIdx.x;
    const int lane = tid & 63, w = tid >> 6;
    const int wm = w & 1, wn = w >> 1;
    const int l15 = lane & 15, q8 = (lane >> 4) * 8;

    __shared__ int toks[64];
    __shared__ __align__(16) ushort As[64][72];
    __shared__ __align__(16) ushort Bs[256][72];

    if (tid < 64) {
        int t  = t0 + tid;
        int tt = dir ? ((t < L) ? (L - 1 - t) : t) : t;
        toks[tid] = (r < B_) ? s1[r * T_ + tt] : s2[(r - B_) * T_ + tt];
    }
    __syncthreads();

    const ushort* Wih  = dir ? WihBb : WihBf;
    const float*  bias = dir ? b_b : b_f;

    f32x4 acc[2][8] = {};

    for (int k0 = 0; k0 < EP; k0 += 64) {
#pragma unroll
        for (int p = 0; p < 2; ++p) {   // A: 64 rows x 64 k
            int u = tid + p * 256;
            int row = u >> 3, seg = u & 7;
            *(uint4*)&As[row][seg * 8] =
                *(const uint4*)&embB[(long)toks[row] * EP + k0 + seg * 8];
        }
#pragma unroll
        for (int p = 0; p < 8; ++p) {   // B: 256 cols x 64 k
            int u = tid + p * 256;
            int row = u >> 3, seg = u & 7;
            *(uint4*)&Bs[row][seg * 8] =
                *(const uint4*)&Wih[(long)(N0 + row) * EP + k0 + seg * 8];
        }
        __syncthreads();
#pragma unroll
        for (int ks = 0; ks < 2; ++ks) {
            bf16x8 af[2], bfr[8];
#pragma unroll
            for (int mt = 0; mt < 2; ++mt)
                af[mt] = *(const bf16x8*)&As[wm * 32 + mt * 16 + l15][ks * 32 + q8];
#pragma unroll
            for (int nt = 0; nt < 8; ++nt)
                bfr[nt] = *(const bf16x8*)&Bs[wn * 128 + nt * 16 + l15][ks * 32 + q8];
#pragma unroll
            for (int mt = 0; mt < 2; ++mt)
#pragma unroll
                for (int nt = 0; nt < 8; ++nt)
                    acc[mt][nt] = MFMA(af[mt], bfr[nt], acc[mt][nt]);
        }
        __syncthreads();
    }

    ushort* xout = dir ? xb : xf;
#pragma unroll
    for (int mt = 0; mt < 2; ++mt) {
        int m = r * T_ + t0 + wm * 32 + mt * 16 + (lane >> 4) * 4;
#pragma unroll
        for (int nt = 0; nt < 8; ++nt) {
            int col = N0 + wn * 128 + nt * 16 + l15;
            float bv = bias[col];
#pragma unroll
            for (int rg = 0; rg < 4; ++rg) {
                uint v = f2bf(acc[mt][nt][rg] + bv);
                uint pv = (uint)__shfl_xor((int)v, 1);
                if (!(lane & 1))
                    *(uint*)&xout[(long)(m + rg) * G4 + col] = v | (pv << 16);
            }
        }
    }
}

// ---------------------------------------------------------------------------
// K2 v8 VERBATIM (round-0 measured 456 us / 3.55 us/step): persistent
// recurrence, dataflow sync via sentinel data-polling, relaxed agent atomics,
// dense reload-all poll. Four protocol variants (v9-v12) all regressed;
// this is the proven local optimum for the cross-block handoff.
// ---------------------------------------------------------------------------
__global__ __launch_bounds__(256) void k_recur(
    const ushort* __restrict__ xf, const ushort* __restrict__ xb,
    ushort* __restrict__ hfB, ushort* __restrict__ hbB,
    const ushort* __restrict__ WhhBf, const ushort* __restrict__ WhhBb,
    const float* __restrict__ s1_c0, const float* __restrict__ s2_c0)
{
    const int bx = blockIdx.x;
    const int s  = bx >> 6;          // stream: 0 fwd, 1 bwd
    const int rb = (bx >> 4) & 3;    // row block of 32
    const int jb = bx & 15;          // j block of 32
    const int r0 = rb * 32, j0 = jb * 32;

    const ushort* xW  = s ? xb : xf;
    const ushort* Whh = s ? WhhBb : WhhBf;
    ushort* hB = s ? hbB : hfB;

    const int tid = threadIdx.x;
    const int lane = tid & 63;
    const int g = tid >> 6;          // wave = gate (i,f,g,o)
    const int l15 = lane & 15, q8 = (lane >> 4) * 8;

    __shared__ __align__(16) ushort As[32][520];   // 32 rows x 512 k, swizzled chunks
    __shared__ float Gs[4][32][33];                // gate pre-acts 32 x 32

    // Whh fragments resident in registers: wave g, 32 cols (2 n-tiles), K=512
    bf16x8 bfr[2][16];
#pragma unroll
    for (int nt = 0; nt < 2; ++nt) {
        const ushort* brow = &Whh[((long)g * H_ + j0 + nt * 16 + l15) * H_];
#pragma unroll
        for (int ks = 0; ks < 16; ++ks)
            bfr[nt][ks] = *(const bf16x8*)&brow[ks * 32 + q8];
    }

    // cell ownership: thread -> (row rr, 4 cols at jj)
    const int rr = tid >> 3, jj = (tid & 7) * 4;
    const int rg_ = r0 + rr;
    const int rl  = (rg_ < B_) ? rg_ : rg_ - B_;
    const float* c0p = (rg_ < B_) ? s1_c0 : s2_c0;   // [2][B][H]
    float cst[4];
#pragma unroll
    for (int cc = 0; cc < 4; ++cc)
        cst[cc] = c0p[(long)s * B_ * H_ + (long)rl * H_ + j0 + jj + cc];

    // A staging: thread -> (row arow, chunk aseg); chunk placed at (aseg+arow)&7
    const int arow = tid >> 3, aseg = tid & 7;
    const int swz = ((aseg + arow) & 7) * 8;

    for (int t = 0; t < T_; ++t) {
        // xW gate pre-activations (4 cols x 4 gates) — issued before the
        // h poll so their latency hides under the wait
        uint2 xw[4];
        const long xbase = ((long)rg_ * T_ + t) * G4 + j0 + jj;
#pragma unroll
        for (int gg = 0; gg < 4; ++gg)
            xw[gg] = *(const uint2*)&xW[xbase + gg * H_];

        // h(t): poll the data itself. 16 x 8B chunks; reload all each pass.
        const ushort* hrow = &hB[((long)(r0 + arow) * TS + t) * H_ + aseg * 8];
        unsigned long long hv[16];
        bool ok;
        do {
#pragma unroll
            for (int i = 0; i < 16; ++i) {
                const unsigned long long* p8 =
                    (const unsigned long long*)(hrow + (i >> 1) * 64 + (i & 1) * 4);
                hv[i] = __hip_atomic_load(p8, __ATOMIC_RELAXED,
                                          __HIP_MEMORY_SCOPE_AGENT);
            }
            ok = true;
#pragma unroll
            for (int i = 0; i < 16; ++i)
                ok = ok && (hv[i] != SENT);
        } while (!ok);

#pragma unroll
        for (int sl = 0; sl < 8; ++sl) {
            uint4 av;
            av.x = (uint)hv[2 * sl];       av.y = (uint)(hv[2 * sl] >> 32);
            av.z = (uint)hv[2 * sl + 1];   av.w = (uint)(hv[2 * sl + 1] >> 32);
            *(uint4*)&As[arow][sl * 64 + swz] = av;
        }
        __syncthreads();

        f32x4 acc[2][2] = {};   // [mtile][ntile]
#pragma unroll
        for (int ks = 0; ks < 16; ++ks) {
            const int e  = ks * 32 + q8;
            const int sl = e >> 6;
            const int c  = (e >> 3) & 7;
            bf16x8 a0 = *(const bf16x8*)&As[l15][sl * 64 + (((c + l15) & 7) << 3)];
            bf16x8 a1 = *(const bf16x8*)&As[16 + l15][sl * 64 + (((c + l15) & 7) << 3)];
            acc[0][0] = MFMA(a0, bfr[0][ks], acc[0][0]);
            acc[0][1] = MFMA(a0, bfr[1][ks], acc[0][1]);
            acc[1][0] = MFMA(a1, bfr[0][ks], acc[1][0]);
            acc[1][1] = MFMA(a1, bfr[1][ks], acc[1][1]);
        }

        // publish gate pre-acts (C layout: col=lane&15, row=(lane>>4)*4+rg)
#pragma unroll
        for (int mt = 0; mt < 2; ++mt)
#pragma unroll
            for (int nt = 0; nt < 2; ++nt)
#pragma unroll
                for (int rg2 = 0; rg2 < 4; ++rg2)
                    Gs[g][mt * 16 + (lane >> 4) * 4 + rg2][nt * 16 + l15] =
                        acc[mt][nt][rg2];
        __syncthreads();

        // fused cell update for 4 cols
        ushort hp[4];
#pragma unroll
        for (int cc = 0; cc < 4; ++cc) {
            uint xv0 = (cc < 2) ? xw[0].x : xw[0].y;
            uint xv1 = (cc < 2) ? xw[1].x : xw[1].y;
            uint xv2 = (cc < 2) ? xw[2].x : xw[2].y;
            uint xv3 = (cc < 2) ? xw[3].x : xw[3].y;
            int sh = (cc & 1) * 16;
            float gi = Gs[0][rr][jj + cc] + bf2f((ushort)(xv0 >> sh));
            float gf = Gs[1][rr][jj + cc] + bf2f((ushort)(xv1 >> sh));
            float gg = Gs[2][rr][jj + cc] + bf2f((ushort)(xv2 >> sh));
            float go = Gs[3][rr][jj + cc] + bf2f((ushort)(xv3 >> sh));
            cst[cc] = fsig(gf) * cst[cc] + fsig(gi) * ftanh(gg);
            hp[cc] = f2bf(fsig(go) * ftanh(cst[cc]));
        }
        unsigned long long pk = (unsigned long long)hp[0]
                              | ((unsigned long long)hp[1] << 16)
                              | ((unsigned long long)hp[2] << 32)
                              | ((unsigned long long)hp[3] << 48);
        __hip_atomic_store(
            (unsigned long long*)&hB[((long)rg_ * TS + t + 1) * H_ + j0 + jj],
            pk, __ATOMIC_RELAXED, __HIP_MEMORY_SCOPE_AGENT);
    }
}

// ---------------------------------------------------------------------------
// K3 FUSED: per-r block computes U = tanh(Hout @ S1W^T) with acc-resident U,
// scores = U @ S2W via in-register dot + shfl reduce + LDS atomicAdd,
// masked softmax, pooled = attn @ Hout. Eliminates the U tensor (33.6 MB
// HBM round-trip) and one kernel launch. Math order identical to K3a+K3b.
// ---------------------------------------------------------------------------
__global__ __launch_bounds__(256) void k_attn_fused(
    const ushort* __restrict__ hfB, const ushort* __restrict__ hbB,
    const int* __restrict__ l1, const int* __restrict__ l2,
    const ushort* __restrict__ S1WB, const float* __restrict__ S2W,
    float* __restrict__ pooled)
{
    const int r = blockIdx.x;
    const int L = (r < B_) ? l1[r] : l2[r - B_];
    const int tid = threadIdx.x;
    const int lane = tid & 63, w = tid >> 6;
    const int wm = w & 1, wn = w >> 1;
    const int l15 = lane & 15, q8 = (lane >> 4) * 8;

    __shared__ __align__(16) ushort As[128][72];   // 128 t-rows x 64 k
    __shared__ __align__(16) ushort Bs[256][72];   // 256 c-rows x 64 k
    __shared__ float sc[T_];
    __shared__ float att[T_];

    if (tid < T_) sc[tid] = 0.0f;

    // GEMM: M=128 (t), N=256 (c), K=1024 (2H); per wave 64 rows x 128 cols
    f32x4 acc[4][8] = {};

    for (int k0 = 0; k0 < 2 * H_; k0 += 64) {
#pragma unroll
        for (int p = 0; p < 4; ++p) {   // A: 128 rows x 64 k
            int u = tid + p * 256;
            int row = u >> 3, seg = u & 7;
            int k = k0 + seg * 8;
            long idx;
            const ushort* src;
            if (k0 < H_) {
                src = hfB; idx = ((long)r * TS + row + 1) * H_ + k;
            } else {
                int tt = (row < L) ? (L - 1 - row) : row;
                src = hbB; idx = ((long)r * TS + tt + 1) * H_ + (k - H_);
            }
            *(uint4*)&As[row][seg * 8] = *(const uint4*)&src[idx];
        }
#pragma unroll
        for (int p = 0; p < 8; ++p) {   // B: 256 c-rows x 64 k
            int u = tid + p * 256;
            int row = u >> 3, seg = u & 7;
            *(uint4*)&Bs[row][seg * 8] =
                *(const uint4*)&S1WB[(long)row * (2 * H_) + k0 + seg * 8];
        }
        __syncthreads();
#pragma unroll
        for (int ks = 0; ks < 2; ++ks) {
            bf16x8 af[4], bfr[8];
#pragma unroll
            for (int mt = 0; mt < 4; ++mt)
                af[mt] = *(const bf16x8*)&As[wm * 64 + mt * 16 + l15][ks * 32 + q8];
#pragma unroll
            for (int nt = 0; nt < 8; ++nt)
                bfr[nt] = *(const bf16x8*)&Bs[wn * 128 + nt * 16 + l15][ks * 32 + q8];
#pragma unroll
            for (int mt = 0; mt < 4; ++mt)
#pragma unroll
                for (int nt = 0; nt < 8; ++nt)
                    acc[mt][nt] = MFMA(af[mt], bfr[nt], acc[mt][nt]);
        }
        __syncthreads();
    }

    // scores: per-thread partial over its 8 col-tiles, shuffle-reduce over
    // the 16 l15 lanes (same quarter), one LDS atomicAdd per row per wave.
    float s2r[8];
#pragma unroll
    for (int nt = 0; nt < 8; ++nt)
        s2r[nt] = S2W[wn * 128 + nt * 16 + l15];
#pragma unroll
    for (int mt = 0; mt < 4; ++mt)
#pragma unroll
        for (int rg = 0; rg < 4; ++rg) {
            float v = 0.0f;
#pragma unroll
            for (int nt = 0; nt < 8; ++nt)
                v += ftanh(acc[mt][nt][rg]) * s2r[nt];
            v += __shfl_xor(v, 1);
            v += __shfl_xor(v, 2);
            v += __shfl_xor(v, 4);
            v += __shfl_xor(v, 8);
            if (l15 == 0)
                atomicAdd(&sc[wm * 64 + mt * 16 + (lane >> 4) * 4 + rg], v);
        }
    __syncthreads();

    // masked softmax over t < L (K3b pattern, source = sc)
    float mx = -1e30f;
    for (int tt = 0; tt < L; ++tt) mx = fmaxf(mx, sc[tt]);
    __syncthreads();
    if (tid < T_) att[tid] = (tid < L) ? __expf(sc[tid] - mx) : 0.0f;
    __syncthreads();
    float sum = 0.0f;
    for (int tt = 0; tt < L; ++tt) sum += att[tt];
    float inv = 1.0f / sum;

    // pool (K3b verbatim)
    for (int p = tid; p < 512; p += 256) {
        float a0 = 0.0f, a1 = 0.0f;
        if (p < 256) {
            int d = p * 2;
            for (int tt = 0; tt < L; ++tt) {
                uint hv = *(const uint*)&hfB[((long)r * TS + tt + 1) * H_ + d];
                a0 += att[tt] * bf2f((ushort)(hv & 0xffff));
                a1 += att[tt] * bf2f((ushort)(hv >> 16));
            }
            pooled[(long)r * (2 * H_) + d]     = a0 * inv;
            pooled[(long)r * (2 * H_) + d + 1] = a1 * inv;
        } else {
            int d = (p - 256) * 2;
            for (int tt = 0; tt < L; ++tt) {
                uint hv = *(const uint*)&hbB[((long)r * TS + (L - tt)) * H_ + d];
                a0 += att[tt] * bf2f((ushort)(hv & 0xffff));
                a1 += att[tt] * bf2f((ushort)(hv >> 16));
            }
            pooled[(long)r * (2 * H_) + H_ + d]     = a0 * inv;
            pooled[(long)r * (2 * H_) + H_ + d + 1] = a1 * inv;
        }
    }
}

// ---------------------------------------------------------------------------
// K4a: om[b][mm] = merged[b] . mlpW[mm] + mlpb[mm] (unchanged).
// ---------------------------------------------------------------------------
__global__ __launch_bounds__(256) void k_mlp1(
    const float* __restrict__ pooled,
    const float* __restrict__ mlpW, const float* __restrict__ mlpb,
    float* __restrict__ om)
{
    const int mg = blockIdx.x;      // 0..7
    const int b  = blockIdx.y;      // 0..63
    const int tid = threadIdx.x;
    const int lane = tid & 63, w = tid >> 6;

    __shared__ __align__(16) float sm[2048];

#pragma unroll
    for (int it = 0; it < 8; ++it) {
        int d = tid + it * 256;
        float v;
        if (d < 1024) {
            v = pooled[(long)b * 1024 + d] + pooled[(long)(B_ + b) * 1024 + d];
        } else {
            int dd = d - 1024;
            float x = pooled[(long)b * 1024 + dd] - pooled[(long)(B_ + b) * 1024 + dd];
            v = x * x;
        }
        sm[d] = v;
    }
    __syncthreads();

    for (int i = 0; i < 16; ++i) {
        int mm = mg * 64 + w * 16 + i;
        const float* wrow = &mlpW[(long)mm * 2048];
        float ax = 0.f, ay = 0.f, az = 0.f, aw = 0.f;
#pragma unroll
        for (int it = 0; it < 8; ++it) {
            int k = it * 256 + lane * 4;
            float4 wv = *(const float4*)&wrow[k];
            float4 sv = *(const float4*)&sm[k];
            ax += wv.x * sv.x; ay += wv.y * sv.y;
            az += wv.z * sv.z; aw += wv.w * sv.w;
        }
        float ssum = (ax + ay) + (az + aw);
        for (int off = 32; off; off >>= 1) ssum += __shfl_down(ssum, off);
        if (lane == 0) om[(long)b * M_ + mm] = ssum + mlpb[mm];
    }
}

// K4b: out[b] = sigmoid(om[b] . outW + outb)   (CLS = 1)
__global__ __launch_bounds__(256) void k_final(
    const float* __restrict__ om,
    const float* __restrict__ outW, const float* __restrict__ outb,
    float* __restrict__ out)
{
    const int b = blockIdx.x;
    const int tid = threadIdx.x;
    __shared__ float red[256];
    float p = om[(long)b * M_ + tid] * outW[tid]
            + om[(long)b * M_ + 256 + tid] * outW[256 + tid];
    red[tid] = p;
    __syncthreads();
    for (int off = 128; off > 0; off >>= 1) {
        if (tid < off) red[tid] += red[tid + off];
        __syncthreads();
    }
    if (tid == 0) out[b] = 1.0f / (1.0f + __expf(-(red[0] + outb[0])));
}

// ---------------------------------------------------------------------------
extern "C" void kernel_launch(void* const* d_in, const int* in_sizes, int n_in,
                              void* d_out, int out_size, void* d_ws, size_t ws_size,
                              hipStream_t stream)
{
    const int*   s1    = (const int*)d_in[0];
    const int*   s2    = (const int*)d_in[1];
    const int*   l1    = (const int*)d_in[2];
    const int*   l2    = (const int*)d_in[3];
    const float* s1_h0 = (const float*)d_in[4];
    const float* s1_c0 = (const float*)d_in[5];
    const float* s2_h0 = (const float*)d_in[6];
    const float* s2_c0 = (const float*)d_in[7];
    const float* emb   = (const float*)d_in[8];
    const float* Wih_f = (const float*)d_in[9];
    const float* Whh_f = (const float*)d_in[10];
    const float* b_f   = (const float*)d_in[11];
    const float* Wih_b = (const float*)d_in[12];
    const float* Whh_b = (const float*)d_in[13];
    const float* b_b   = (const float*)d_in[14];
    const float* S1W   = (const float*)d_in[15];
    const float* S2W   = (const float*)d_in[16];
    const float* mlpW  = (const float*)d_in[17];
    const float* mlpb  = (const float*)d_in[18];
    const float* outW  = (const float*)d_in[19];
    const float* outb  = (const float*)d_in[20];
    float* out = (float*)d_out;

    // Workspace carve (all 16B-aligned); U eliminated by the K3 fusion.
    ushort* p16 = (ushort*)d_ws;
    ushort* embB  = p16;  p16 += (long)32000 * EP;
    ushort* WihBf = p16;  p16 += (long)G4 * EP;
    ushort* WihBb = p16;  p16 += (long)G4 * EP;
    ushort* WhhBf = p16;  p16 += (long)G4 * H_;
    ushort* WhhBb = p16;  p16 += (long)G4 * H_;
    ushort* S1WB  = p16;  p16 += (long)C_ * 2 * H_;
    ushort* xf    = p16;  p16 += (long)R_ * T_ * G4;
    ushort* xb    = p16;  p16 += (long)R_ * T_ * G4;
    ushort* hfB   = p16;  p16 += (long)R_ * TS * H_;
    ushort* hbB   = p16;  p16 += (long)R_ * TS * H_;
    float* pf = (float*)p16;
    float* pooled = pf;   pf += (long)R_ * 2 * H_;
    float* om     = pf;   pf += (long)B_ * M_;

    // sentinel-fill h arrays (0xFF bytes -> every 8B chunk = SENT); the
    // cvt_all init-role then writes real h0 into slot 0. hfB/hbB contiguous.
    hipMemsetAsync(hfB, 0xFF, (size_t)2 * R_ * TS * H_ * sizeof(ushort), stream);

    // P0: fused weight conversion + h0 init (one launch)
    k_cvt_all<<<40576, 256, 0, stream>>>(emb, Wih_f, Wih_b, Whh_f, Whh_b, S1W,
                                         s1_h0, s2_h0,
                                         embB, WihBf, WihBb, WhhBf, WhhBb, S1WB,
                                         hfB, hbB);

    // K1: input GEMM (64x256 tile, BK=64)
    k_embed_mfma<<<dim3(8, 256, 2), 256, 0, stream>>>(
        s1, s2, l1, l2, embB, WihBf, WihBb, b_f, b_b, xf, xb);

    // K2: full recurrence in ONE persistent launch (v8 dataflow sync)
    k_recur<<<NB, 256, 0, stream>>>(xf, xb, hfB, hbB, WhhBf, WhhBb,
                                    s1_c0, s2_c0);

    // K3: fused attention (GEMM + scores + softmax + pool, U eliminated)
    k_attn_fused<<<R_, 256, 0, stream>>>(hfB, hbB, l1, l2, S1WB, S2W, pooled);

    // K4: MLP head
    k_mlp1<<<dim3(8, B_), 256, 0, stream>>>(pooled, mlpW, mlpb, om);
    k_final<<<B_, 256, 0, stream>>>(om, outW, outb, out);
}

// Round 6
// 791.551 us; speedup vs baseline: 2.6040x; 1.0142x over previous
//
#include <hip/hip_runtime.h>
#include <hip/hip_bf16.h>

// Problem constants (fixed by the reference)
#define B_  64
#define T_  128
#define E_  300
#define EP  320     // E padded to multiple of 32 for MFMA K-loop
#define H_  512
#define G4  2048    // 4*H
#define R_  128     // 2*B (s1+s2 batched; shared LSTM weights)
#define C_  256
#define M_  512
#define TS  (T_ + 1)  // h time slots: slot 0 = h0, slot t+1 = h(t)
#define NB  128     // persistent-kernel grid: 2 streams x 4 rowblocks x 16 jblocks
#define SENT 0xFFFFFFFFFFFFFFFFULL   // 4x bf16 NaN — unreachable by real h

typedef short bf16x8 __attribute__((ext_vector_type(8)));
typedef float f32x4  __attribute__((ext_vector_type(4)));
#define MFMA(a, b, c) __builtin_amdgcn_mfma_f32_16x16x32_bf16((a), (b), (c), 0, 0, 0)

__device__ __forceinline__ float fsig(float x) { return 1.0f / (1.0f + __expf(-x)); }
__device__ __forceinline__ float ftanh(float x) {
    float a = fminf(fabsf(x), 15.0f);
    float e = __expf(2.0f * a);
    return copysignf((e - 1.0f) / (e + 1.0f), x);
}
__device__ __forceinline__ ushort f2bf(float f) {
    __hip_bfloat16 h = __float2bfloat16(f);
    return *reinterpret_cast<ushort*>(&h);
}
__device__ __forceinline__ float bf2f(ushort u) {
    __hip_bfloat16 h = *reinterpret_cast<__hip_bfloat16*>(&u);
    return __bfloat162float(h);
}

// ---------------------------------------------------------------------------
// P0 v2: VECTORIZED f32 -> bf16 conversion (Common-mistake-#2 fix).
// 8 elements/thread: 2x float4 load + one 16B bf16x8 store; 8 rows/block.
// Blocks: [0,4000) emb, [4000,4256) Wih_f, [4256,4512) Wih_b,
//         [4512,4768) Whh_f, [4768,5024) Whh_b, [5024,5056) S1W,
//         [5056,5184) h0 init (after 0xFF sentinel memset).
// Guarded tail handles the E=300 (not %8) edge; pad region [sk,dk) -> 0.
// ---------------------------------------------------------------------------
__global__ __launch_bounds__(256) void k_cvt_all(
    const float* __restrict__ emb,
    const float* __restrict__ Wih_f, const float* __restrict__ Wih_b,
    const float* __restrict__ Whh_f, const float* __restrict__ Whh_b,
    const float* __restrict__ S1W,
    const float* __restrict__ s1_h0, const float* __restrict__ s2_h0,
    ushort* __restrict__ embB,
    ushort* __restrict__ WihBf, ushort* __restrict__ WihBb,
    ushort* __restrict__ WhhBf, ushort* __restrict__ WhhBb,
    ushort* __restrict__ S1WB,
    ushort* __restrict__ hfB, ushort* __restrict__ hbB)
{
    const int b = blockIdx.x;
    if (b >= 5056) {   // h0 init role: 128 blocks, one r each
        const int r = b - 5056;                      // 0..127
        const int rl = (r < B_) ? r : r - B_;
        const float* h0 = (r < B_) ? s1_h0 : s2_h0;  // [2][B][H]
        for (int u = threadIdx.x; u < 128; u += 256) {
            const int which = u >> 6;                // 0: fwd/hf, 1: bwd/hb
            const int c8 = (u & 63) * 8;
            const float* s = h0 + (long)which * B_ * H_ + (long)rl * H_ + c8;
            ushort* d = (which ? hbB : hfB) + (long)r * TS * H_ + c8;
            float4 f0 = *(const float4*)&s[0];
            float4 f1 = *(const float4*)&s[4];
            bf16x8 v;
            v[0] = (short)f2bf(f0.x); v[1] = (short)f2bf(f0.y);
            v[2] = (short)f2bf(f0.z); v[3] = (short)f2bf(f0.w);
            v[4] = (short)f2bf(f1.x); v[5] = (short)f2bf(f1.y);
            v[6] = (short)f2bf(f1.z); v[7] = (short)f2bf(f1.w);
            *(bf16x8*)d = v;
        }
        return;
    }
    const float* src; ushort* dst; int r0, sk, dk;
    if (b < 4000)      { src = emb;   dst = embB;  r0 = b * 8;          sk = E_;    dk = EP; }
    else if (b < 4256) { src = Wih_f; dst = WihBf; r0 = (b - 4000) * 8; sk = E_;    dk = EP; }
    else if (b < 4512) { src = Wih_b; dst = WihBb; r0 = (b - 4256) * 8; sk = E_;    dk = EP; }
    else if (b < 4768) { src = Whh_f; dst = WhhBf; r0 = (b - 4512) * 8; sk = H_;    dk = H_; }
    else if (b < 5024) { src = Whh_b; dst = WhhBb; r0 = (b - 4768) * 8; sk = H_;    dk = H_; }
    else               { src = S1W;   dst = S1WB;  r0 = (b - 5024) * 8; sk = 2*H_;  dk = 2*H_; }
    const int upr = dk >> 3;            // 8-elem units per row
    for (int u = threadIdx.x; u < 8 * upr; u += 256) {
        const int r  = r0 + u / upr;
        const int c8 = (u % upr) * 8;
        const float* s = &src[(long)r * sk + c8];
        bf16x8 v;
        if (c8 + 8 <= sk) {
            float4 f0 = *(const float4*)&s[0];
            float4 f1 = *(const float4*)&s[4];
            v[0] = (short)f2bf(f0.x); v[1] = (short)f2bf(f0.y);
            v[2] = (short)f2bf(f0.z); v[3] = (short)f2bf(f0.w);
            v[4] = (short)f2bf(f1.x); v[5] = (short)f2bf(f1.y);
            v[6] = (short)f2bf(f1.z); v[7] = (short)f2bf(f1.w);
        } else {
#pragma unroll
            for (int e = 0; e < 8; ++e)
                v[e] = (c8 + e < sk) ? (short)f2bf(s[e]) : (short)0;
        }
        *(bf16x8*)&dst[(long)r * dk + c8] = v;
    }
}

// ---------------------------------------------------------------------------
// K1 v2: embedding gather + input GEMM via bf16 MFMA (round-5 verbatim).
// Tile 64x256, BK=64; L<=t0 early-exit; shfl_xor(1) paired 4B stores.
// ---------------------------------------------------------------------------
__global__ __launch_bounds__(256) void k_embed_mfma(
    const int* __restrict__ s1, const int* __restrict__ s2,
    const int* __restrict__ l1, const int* __restrict__ l2,
    const ushort* __restrict__ embB,
    const ushort* __restrict__ WihBf, const ushort* __restrict__ WihBb,
    const float* __restrict__ b_f, const float* __restrict__ b_b,
    ushort* __restrict__ xf, ushort* __restrict__ xb)
{
    const int dir = blockIdx.z;
    const int r   = blockIdx.y >> 1;
    const int t0  = (blockIdx.y & 1) * 64;
    const int N0  = blockIdx.x * 256;
    const int L   = (r < B_) ? l1[r] : l2[r - B_];
    if (L <= t0) return;

    const int tid = threadIdx.x;
    const int lane = tid & 63, w = tid >> 6;
    const int wm = w & 1, wn = w >> 1;
    const int l15 = lane & 15, q8 = (lane >> 4) * 8;

    __shared__ int toks[64];
    __shared__ __align__(16) ushort As[64][72];
    __shared__ __align__(16) ushort Bs[256][72];

    if (tid < 64) {
        int t  = t0 + tid;
        int tt = dir ? ((t < L) ? (L - 1 - t) : t) : t;
        toks[tid] = (r < B_) ? s1[r * T_ + tt] : s2[(r - B_) * T_ + tt];
    }
    __syncthreads();

    const ushort* Wih  = dir ? WihBb : WihBf;
    const float*  bias = dir ? b_b : b_f;

    f32x4 acc[2][8] = {};

    for (int k0 = 0; k0 < EP; k0 += 64) {
#pragma unroll
        for (int p = 0; p < 2; ++p) {   // A: 64 rows x 64 k
            int u = tid + p * 256;
            int row = u >> 3, seg = u & 7;
            *(uint4*)&As[row][seg * 8] =
                *(const uint4*)&embB[(long)toks[row] * EP + k0 + seg * 8];
        }
#pragma unroll
        for (int p = 0; p < 8; ++p) {   // B: 256 cols x 64 k
            int u = tid + p * 256;
            int row = u >> 3, seg = u & 7;
            *(uint4*)&Bs[row][seg * 8] =
                *(const uint4*)&Wih[(long)(N0 + row) * EP + k0 + seg * 8];
        }
        __syncthreads();
#pragma unroll
        for (int ks = 0; ks < 2; ++ks) {
            bf16x8 af[2], bfr[8];
#pragma unroll
            for (int mt = 0; mt < 2; ++mt)
                af[mt] = *(const bf16x8*)&As[wm * 32 + mt * 16 + l15][ks * 32 + q8];
#pragma unroll
            for (int nt = 0; nt < 8; ++nt)
                bfr[nt] = *(const bf16x8*)&Bs[wn * 128 + nt * 16 + l15][ks * 32 + q8];
#pragma unroll
            for (int mt = 0; mt < 2; ++mt)
#pragma unroll
                for (int nt = 0; nt < 8; ++nt)
                    acc[mt][nt] = MFMA(af[mt], bfr[nt], acc[mt][nt]);
        }
        __syncthreads();
    }

    ushort* xout = dir ? xb : xf;
#pragma unroll
    for (int mt = 0; mt < 2; ++mt) {
        int m = r * T_ + t0 + wm * 32 + mt * 16 + (lane >> 4) * 4;
#pragma unroll
        for (int nt = 0; nt < 8; ++nt) {
            int col = N0 + wn * 128 + nt * 16 + l15;
            float bv = bias[col];
#pragma unroll
            for (int rg = 0; rg < 4; ++rg) {
                uint v = f2bf(acc[mt][nt][rg] + bv);
                uint pv = (uint)__shfl_xor((int)v, 1);
                if (!(lane & 1))
                    *(uint*)&xout[(long)(m + rg) * G4 + col] = v | (pv << 16);
            }
        }
    }
}

// ---------------------------------------------------------------------------
// K2 v8 VERBATIM (measured 453-456 us / 3.55 us/step): persistent recurrence,
// dataflow sync via sentinel data-polling, relaxed agent atomics, dense
// reload-all poll. Protocol variants v9-v12 all regressed; local optimum.
// ---------------------------------------------------------------------------
__global__ __launch_bounds__(256) void k_recur(
    const ushort* __restrict__ xf, const ushort* __restrict__ xb,
    ushort* __restrict__ hfB, ushort* __restrict__ hbB,
    const ushort* __restrict__ WhhBf, const ushort* __restrict__ WhhBb,
    const float* __restrict__ s1_c0, const float* __restrict__ s2_c0)
{
    const int bx = blockIdx.x;
    const int s  = bx >> 6;          // stream: 0 fwd, 1 bwd
    const int rb = (bx >> 4) & 3;    // row block of 32
    const int jb = bx & 15;          // j block of 32
    const int r0 = rb * 32, j0 = jb * 32;

    const ushort* xW  = s ? xb : xf;
    const ushort* Whh = s ? WhhBb : WhhBf;
    ushort* hB = s ? hbB : hfB;

    const int tid = threadIdx.x;
    const int lane = tid & 63;
    const int g = tid >> 6;          // wave = gate (i,f,g,o)
    const int l15 = lane & 15, q8 = (lane >> 4) * 8;

    __shared__ __align__(16) ushort As[32][520];   // 32 rows x 512 k, swizzled chunks
    __shared__ float Gs[4][32][33];                // gate pre-acts 32 x 32

    // Whh fragments resident in registers: wave g, 32 cols (2 n-tiles), K=512
    bf16x8 bfr[2][16];
#pragma unroll
    for (int nt = 0; nt < 2; ++nt) {
        const ushort* brow = &Whh[((long)g * H_ + j0 + nt * 16 + l15) * H_];
#pragma unroll
        for (int ks = 0; ks < 16; ++ks)
            bfr[nt][ks] = *(const bf16x8*)&brow[ks * 32 + q8];
    }

    // cell ownership: thread -> (row rr, 4 cols at jj)
    const int rr = tid >> 3, jj = (tid & 7) * 4;
    const int rg_ = r0 + rr;
    const int rl  = (rg_ < B_) ? rg_ : rg_ - B_;
    const float* c0p = (rg_ < B_) ? s1_c0 : s2_c0;   // [2][B][H]
    float cst[4];
#pragma unroll
    for (int cc = 0; cc < 4; ++cc)
        cst[cc] = c0p[(long)s * B_ * H_ + (long)rl * H_ + j0 + jj + cc];

    // A staging: thread -> (row arow, chunk aseg); chunk placed at (aseg+arow)&7
    const int arow = tid >> 3, aseg = tid & 7;
    const int swz = ((aseg + arow) & 7) * 8;

    for (int t = 0; t < T_; ++t) {
        // xW gate pre-activations (4 cols x 4 gates) — issued before the
        // h poll so their latency hides under the wait
        uint2 xw[4];
        const long xbase = ((long)rg_ * T_ + t) * G4 + j0 + jj;
#pragma unroll
        for (int gg = 0; gg < 4; ++gg)
            xw[gg] = *(const uint2*)&xW[xbase + gg * H_];

        // h(t): poll the data itself. 16 x 8B chunks; reload all each pass.
        const ushort* hrow = &hB[((long)(r0 + arow) * TS + t) * H_ + aseg * 8];
        unsigned long long hv[16];
        bool ok;
        do {
#pragma unroll
            for (int i = 0; i < 16; ++i) {
                const unsigned long long* p8 =
                    (const unsigned long long*)(hrow + (i >> 1) * 64 + (i & 1) * 4);
                hv[i] = __hip_atomic_load(p8, __ATOMIC_RELAXED,
                                          __HIP_MEMORY_SCOPE_AGENT);
            }
            ok = true;
#pragma unroll
            for (int i = 0; i < 16; ++i)
                ok = ok && (hv[i] != SENT);
        } while (!ok);

#pragma unroll
        for (int sl = 0; sl < 8; ++sl) {
            uint4 av;
            av.x = (uint)hv[2 * sl];       av.y = (uint)(hv[2 * sl] >> 32);
            av.z = (uint)hv[2 * sl + 1];   av.w = (uint)(hv[2 * sl + 1] >> 32);
            *(uint4*)&As[arow][sl * 64 + swz] = av;
        }
        __syncthreads();

        f32x4 acc[2][2] = {};   // [mtile][ntile]
#pragma unroll
        for (int ks = 0; ks < 16; ++ks) {
            const int e  = ks * 32 + q8;
            const int sl = e >> 6;
            const int c  = (e >> 3) & 7;
            bf16x8 a0 = *(const bf16x8*)&As[l15][sl * 64 + (((c + l15) & 7) << 3)];
            bf16x8 a1 = *(const bf16x8*)&As[16 + l15][sl * 64 + (((c + l15) & 7) << 3)];
            acc[0][0] = MFMA(a0, bfr[0][ks], acc[0][0]);
            acc[0][1] = MFMA(a0, bfr[1][ks], acc[0][1]);
            acc[1][0] = MFMA(a1, bfr[0][ks], acc[1][0]);
            acc[1][1] = MFMA(a1, bfr[1][ks], acc[1][1]);
        }

        // publish gate pre-acts (C layout: col=lane&15, row=(lane>>4)*4+rg)
#pragma unroll
        for (int mt = 0; mt < 2; ++mt)
#pragma unroll
            for (int nt = 0; nt < 2; ++nt)
#pragma unroll
                for (int rg2 = 0; rg2 < 4; ++rg2)
                    Gs[g][mt * 16 + (lane >> 4) * 4 + rg2][nt * 16 + l15] =
                        acc[mt][nt][rg2];
        __syncthreads();

        // fused cell update for 4 cols
        ushort hp[4];
#pragma unroll
        for (int cc = 0; cc < 4; ++cc) {
            uint xv0 = (cc < 2) ? xw[0].x : xw[0].y;
            uint xv1 = (cc < 2) ? xw[1].x : xw[1].y;
            uint xv2 = (cc < 2) ? xw[2].x : xw[2].y;
            uint xv3 = (cc < 2) ? xw[3].x : xw[3].y;
            int sh = (cc & 1) * 16;
            float gi = Gs[0][rr][jj + cc] + bf2f((ushort)(xv0 >> sh));
            float gf = Gs[1][rr][jj + cc] + bf2f((ushort)(xv1 >> sh));
            float gg = Gs[2][rr][jj + cc] + bf2f((ushort)(xv2 >> sh));
            float go = Gs[3][rr][jj + cc] + bf2f((ushort)(xv3 >> sh));
            cst[cc] = fsig(gf) * cst[cc] + fsig(gi) * ftanh(gg);
            hp[cc] = f2bf(fsig(go) * ftanh(cst[cc]));
        }
        unsigned long long pk = (unsigned long long)hp[0]
                              | ((unsigned long long)hp[1] << 16)
                              | ((unsigned long long)hp[2] << 32)
                              | ((unsigned long long)hp[3] << 48);
        __hip_atomic_store(
            (unsigned long long*)&hB[((long)rg_ * TS + t + 1) * H_ + j0 + jj],
            pk, __ATOMIC_RELAXED, __HIP_MEMORY_SCOPE_AGENT);
    }
}

// ---------------------------------------------------------------------------
// K3 FUSED (round-5 verbatim, passed): U acc-resident, scores via shfl
// reduce + LDS atomicAdd, masked softmax, pool. U tensor eliminated.
// ---------------------------------------------------------------------------
__global__ __launch_bounds__(256) void k_attn_fused(
    const ushort* __restrict__ hfB, const ushort* __restrict__ hbB,
    const int* __restrict__ l1, const int* __restrict__ l2,
    const ushort* __restrict__ S1WB, const float* __restrict__ S2W,
    float* __restrict__ pooled)
{
    const int r = blockIdx.x;
    const int L = (r < B_) ? l1[r] : l2[r - B_];
    const int tid = threadIdx.x;
    const int lane = tid & 63, w = tid >> 6;
    const int wm = w & 1, wn = w >> 1;
    const int l15 = lane & 15, q8 = (lane >> 4) * 8;

    __shared__ __align__(16) ushort As[128][72];   // 128 t-rows x 64 k
    __shared__ __align__(16) ushort Bs[256][72];   // 256 c-rows x 64 k
    __shared__ float sc[T_];
    __shared__ float att[T_];

    if (tid < T_) sc[tid] = 0.0f;

    // GEMM: M=128 (t), N=256 (c), K=1024 (2H); per wave 64 rows x 128 cols
    f32x4 acc[4][8] = {};

    for (int k0 = 0; k0 < 2 * H_; k0 += 64) {
#pragma unroll
        for (int p = 0; p < 4; ++p) {   // A: 128 rows x 64 k
            int u = tid + p * 256;
            int row = u >> 3, seg = u & 7;
            int k = k0 + seg * 8;
            long idx;
            const ushort* src;
            if (k0 < H_) {
                src = hfB; idx = ((long)r * TS + row + 1) * H_ + k;
            } else {
                int tt = (row < L) ? (L - 1 - row) : row;
                src = hbB; idx = ((long)r * TS + tt + 1) * H_ + (k - H_);
            }
            *(uint4*)&As[row][seg * 8] = *(const uint4*)&src[idx];
        }
#pragma unroll
        for (int p = 0; p < 8; ++p) {   // B: 256 c-rows x 64 k
            int u = tid + p * 256;
            int row = u >> 3, seg = u & 7;
            *(uint4*)&Bs[row][seg * 8] =
                *(const uint4*)&S1WB[(long)row * (2 * H_) + k0 + seg * 8];
        }
        __syncthreads();
#pragma unroll
        for (int ks = 0; ks < 2; ++ks) {
            bf16x8 af[4], bfr[8];
#pragma unroll
            for (int mt = 0; mt < 4; ++mt)
                af[mt] = *(const bf16x8*)&As[wm * 64 + mt * 16 + l15][ks * 32 + q8];
#pragma unroll
            for (int nt = 0; nt < 8; ++nt)
                bfr[nt] = *(const bf16x8*)&Bs[wn * 128 + nt * 16 + l15][ks * 32 + q8];
#pragma unroll
            for (int mt = 0; mt < 4; ++mt)
#pragma unroll
                for (int nt = 0; nt < 8; ++nt)
                    acc[mt][nt] = MFMA(af[mt], bfr[nt], acc[mt][nt]);
        }
        __syncthreads();
    }

    // scores: per-thread partial over its 8 col-tiles, shuffle-reduce over
    // the 16 l15 lanes (same quarter), one LDS atomicAdd per row per wave.
    float s2r[8];
#pragma unroll
    for (int nt = 0; nt < 8; ++nt)
        s2r[nt] = S2W[wn * 128 + nt * 16 + l15];
#pragma unroll
    for (int mt = 0; mt < 4; ++mt)
#pragma unroll
        for (int rg = 0; rg < 4; ++rg) {
            float v = 0.0f;
#pragma unroll
            for (int nt = 0; nt < 8; ++nt)
                v += ftanh(acc[mt][nt][rg]) * s2r[nt];
            v += __shfl_xor(v, 1);
            v += __shfl_xor(v, 2);
            v += __shfl_xor(v, 4);
            v += __shfl_xor(v, 8);
            if (l15 == 0)
                atomicAdd(&sc[wm * 64 + mt * 16 + (lane >> 4) * 4 + rg], v);
        }
    __syncthreads();

    // masked softmax over t < L
    float mx = -1e30f;
    for (int tt = 0; tt < L; ++tt) mx = fmaxf(mx, sc[tt]);
    __syncthreads();
    if (tid < T_) att[tid] = (tid < L) ? __expf(sc[tid] - mx) : 0.0f;
    __syncthreads();
    float sum = 0.0f;
    for (int tt = 0; tt < L; ++tt) sum += att[tt];
    float inv = 1.0f / sum;

    // pool
    for (int p = tid; p < 512; p += 256) {
        float a0 = 0.0f, a1 = 0.0f;
        if (p < 256) {
            int d = p * 2;
            for (int tt = 0; tt < L; ++tt) {
                uint hv = *(const uint*)&hfB[((long)r * TS + tt + 1) * H_ + d];
                a0 += att[tt] * bf2f((ushort)(hv & 0xffff));
                a1 += att[tt] * bf2f((ushort)(hv >> 16));
            }
            pooled[(long)r * (2 * H_) + d]     = a0 * inv;
            pooled[(long)r * (2 * H_) + d + 1] = a1 * inv;
        } else {
            int d = (p - 256) * 2;
            for (int tt = 0; tt < L; ++tt) {
                uint hv = *(const uint*)&hbB[((long)r * TS + (L - tt)) * H_ + d];
                a0 += att[tt] * bf2f((ushort)(hv & 0xffff));
                a1 += att[tt] * bf2f((ushort)(hv >> 16));
            }
            pooled[(long)r * (2 * H_) + H_ + d]     = a0 * inv;
            pooled[(long)r * (2 * H_) + H_ + d + 1] = a1 * inv;
        }
    }
}

// ---------------------------------------------------------------------------
// K4a: om[b][mm] = merged[b] . mlpW[mm] + mlpb[mm] (unchanged).
// ---------------------------------------------------------------------------
__global__ __launch_bounds__(256) void k_mlp1(
    const float* __restrict__ pooled,
    const float* __restrict__ mlpW, const float* __restrict__ mlpb,
    float* __restrict__ om)
{
    const int mg = blockIdx.x;      // 0..7
    const int b  = blockIdx.y;      // 0..63
    const int tid = threadIdx.x;
    const int lane = tid & 63, w = tid >> 6;

    __shared__ __align__(16) float sm[2048];

#pragma unroll
    for (int it = 0; it < 8; ++it) {
        int d = tid + it * 256;
        float v;
        if (d < 1024) {
            v = pooled[(long)b * 1024 + d] + pooled[(long)(B_ + b) * 1024 + d];
        } else {
            int dd = d - 1024;
            float x = pooled[(long)b * 1024 + dd] - pooled[(long)(B_ + b) * 1024 + dd];
            v = x * x;
        }
        sm[d] = v;
    }
    __syncthreads();

    for (int i = 0; i < 16; ++i) {
        int mm = mg * 64 + w * 16 + i;
        const float* wrow = &mlpW[(long)mm * 2048];
        float ax = 0.f, ay = 0.f, az = 0.f, aw = 0.f;
#pragma unroll
        for (int it = 0; it < 8; ++it) {
            int k = it * 256 + lane * 4;
            float4 wv = *(const float4*)&wrow[k];
            float4 sv = *(const float4*)&sm[k];
            ax += wv.x * sv.x; ay += wv.y * sv.y;
            az += wv.z * sv.z; aw += wv.w * sv.w;
        }
        float ssum = (ax + ay) + (az + aw);
        for (int off = 32; off; off >>= 1) ssum += __shfl_down(ssum, off);
        if (lane == 0) om[(long)b * M_ + mm] = ssum + mlpb[mm];
    }
}

// K4b: out[b] = sigmoid(om[b] . outW + outb)   (CLS = 1)
__global__ __launch_bounds__(256) void k_final(
    const float* __restrict__ om,
    const float* __restrict__ outW, const float* __restrict__ outb,
    float* __restrict__ out)
{
    const int b = blockIdx.x;
    const int tid = threadIdx.x;
    __shared__ float red[256];
    float p = om[(long)b * M_ + tid] * outW[tid]
            + om[(long)b * M_ + 256 + tid] * outW[256 + tid];
    red[tid] = p;
    __syncthreads();
    for (int off = 128; off > 0; off >>= 1) {
        if (tid < off) red[tid] += red[tid + off];
        __syncthreads();
    }
    if (tid == 0) out[b] = 1.0f / (1.0f + __expf(-(red[0] + outb[0])));
}

// ---------------------------------------------------------------------------
extern "C" void kernel_launch(void* const* d_in, const int* in_sizes, int n_in,
                              void* d_out, int out_size, void* d_ws, size_t ws_size,
                              hipStream_t stream)
{
    const int*   s1    = (const int*)d_in[0];
    const int*   s2    = (const int*)d_in[1];
    const int*   l1    = (const int*)d_in[2];
    const int*   l2    = (const int*)d_in[3];
    const float* s1_h0 = (const float*)d_in[4];
    const float* s1_c0 = (const float*)d_in[5];
    const float* s2_h0 = (const float*)d_in[6];
    const float* s2_c0 = (const float*)d_in[7];
    const float* emb   = (const float*)d_in[8];
    const float* Wih_f = (const float*)d_in[9];
    const float* Whh_f = (const float*)d_in[10];
    const float* b_f   = (const float*)d_in[11];
    const float* Wih_b = (const float*)d_in[12];
    const float* Whh_b = (const float*)d_in[13];
    const float* b_b   = (const float*)d_in[14];
    const float* S1W   = (const float*)d_in[15];
    const float* S2W   = (const float*)d_in[16];
    const float* mlpW  = (const float*)d_in[17];
    const float* mlpb  = (const float*)d_in[18];
    const float* outW  = (const float*)d_in[19];
    const float* outb  = (const float*)d_in[20];
    float* out = (float*)d_out;

    // Workspace carve (all 16B-aligned)
    ushort* p16 = (ushort*)d_ws;
    ushort* embB  = p16;  p16 += (long)32000 * EP;
    ushort* WihBf = p16;  p16 += (long)G4 * EP;
    ushort* WihBb = p16;  p16 += (long)G4 * EP;
    ushort* WhhBf = p16;  p16 += (long)G4 * H_;
    ushort* WhhBb = p16;  p16 += (long)G4 * H_;
    ushort* S1WB  = p16;  p16 += (long)C_ * 2 * H_;
    ushort* xf    = p16;  p16 += (long)R_ * T_ * G4;
    ushort* xb    = p16;  p16 += (long)R_ * T_ * G4;
    ushort* hfB   = p16;  p16 += (long)R_ * TS * H_;
    ushort* hbB   = p16;  p16 += (long)R_ * TS * H_;
    float* pf = (float*)p16;
    float* pooled = pf;   pf += (long)R_ * 2 * H_;
    float* om     = pf;   pf += (long)B_ * M_;

    // sentinel-fill h arrays (0xFF bytes -> every 8B chunk = SENT); the
    // cvt_all init-role then writes real h0 into slot 0. hfB/hbB contiguous.
    hipMemsetAsync(hfB, 0xFF, (size_t)2 * R_ * TS * H_ * sizeof(ushort), stream);

    // P0 v2: vectorized weight conversion + h0 init
    k_cvt_all<<<5184, 256, 0, stream>>>(emb, Wih_f, Wih_b, Whh_f, Whh_b, S1W,
                                        s1_h0, s2_h0,
                                        embB, WihBf, WihBb, WhhBf, WhhBb, S1WB,
                                        hfB, hbB);

    // K1: input GEMM (64x256 tile, BK=64)
    k_embed_mfma<<<dim3(8, 256, 2), 256, 0, stream>>>(
        s1, s2, l1, l2, embB, WihBf, WihBb, b_f, b_b, xf, xb);

    // K2: full recurrence in ONE persistent launch (v8 dataflow sync)
    k_recur<<<NB, 256, 0, stream>>>(xf, xb, hfB, hbB, WhhBf, WhhBb,
                                    s1_c0, s2_c0);

    // K3: fused attention (GEMM + scores + softmax + pool)
    k_attn_fused<<<R_, 256, 0, stream>>>(hfB, hbB, l1, l2, S1WB, S2W, pooled);

    // K4: MLP head
    k_mlp1<<<dim3(8, B_), 256, 0, stream>>>(pooled, mlpW, mlpb, om);
    k_final<<<B_, 256, 0, stream>>>(om, outW, outb, out);
}